// Round 12
// baseline (3776.400 us; speedup 1.0000x reference)
//
#include <hip/hip_runtime.h>

// TransformerDecoder scan: B=128 independent sequences, one workgroup each.
// Round-11 resubmit (r11 hit GPUAcquisitionTimeout — never benched).
// NT 512->1024 (16 waves, 4 waves/SIMD — was 2; latency hiding was the
// measured gap: active-CU VALUBusy 54%, MfmaUtil 17%, rest stalls).
// FFN per-wave blocks 8->4; two-stage cross-wave reduce keeps red at 32KB.
// Attention 8-way (R<=32) / 4-way (R>32). FFN 3-term hi/lo arithmetic,
// repack, row-t decoder specialization: FROZEN from r10 (3473us, absmax
// 0.015625; h-lo term is load-bearing — scan amplifies ~x800).

typedef __attribute__((ext_vector_type(8))) short short8;
typedef __attribute__((ext_vector_type(4))) float floatx4;
typedef __attribute__((ext_vector_type(4))) unsigned uint4v;

#define DEV static __device__ __forceinline__

namespace {
constexpr int D   = 8;
constexpr int T   = 60;
constexpr int DFF = 2048;
constexpr int SD  = 17;
constexpr int NT  = 1024;            // 16 waves
constexpr int NW  = NT / 64;
constexpr int NRED = 8;              // red slots (two-stage reduce)
constexpr int NBLK = DFF / 32;       // 64 blocks of 32 hidden cols
constexpr int BPW  = NBLK / NW;      // 4 blocks per wave
constexpr int LSTR = NBLK * 2048;    // shorts per layer in ws (256KB)
}

struct Params { const float* in[39]; float* out; };

// fp32 -> bf16 (round-half-up) — repack-time only
DEV unsigned short f2bf(float f) {
  unsigned u = __builtin_bit_cast(unsigned, f);
  return (unsigned short)((u + 0x8000u) >> 16);
}
DEV float bf2f(unsigned short h) {
  unsigned u = ((unsigned)h) << 16;
  return __builtin_bit_cast(float, u);
}
DEV floatx4 mfma16(short8 a, short8 b, floatx4 c) {
  return __builtin_amdgcn_mfma_f32_16x16x32_bf16(a, b, c, 0, 0, 0);
}
// packed fp32->bf16 (RTNE), 2 values -> 1 dword. No builtin on gfx950.
DEV unsigned cvtpk(float lo, float hi) {
  unsigned r;
  asm("v_cvt_pk_bf16_f32 %0, %1, %2" : "=v"(r) : "v"(lo), "v"(hi));
  return r;
}
DEV float lo2f(unsigned u) { return __builtin_bit_cast(float, u << 16); }
DEV float hi2f(unsigned u) { return __builtin_bit_cast(float, u & 0xffff0000u); }
DEV short8 pack4(unsigned a, unsigned b, unsigned c, unsigned d) {
  uint4v u = {a, b, c, d};
  return __builtin_bit_cast(short8, u);
}

// ---------------------------------------------------------------------------
// Repack kernel: per (layer L, 32-hidden block blk) write 2048 shorts:
//   [0:512) W1 A-frag tile 2*blk | [512:1024) tile 2*blk+1
//   [1024:1536) W2 A-frag hi     | [1536:2048) W2 A-frag lo
// W1 A-frag lane (gg,rr): gg0=hi(W1[j0+rr][0..7]) gg1=lo gg2=hi(dup)
//                         gg3={b1_hi,b1_lo,0..} (bias folded, B supplies 1.0)
// W2 A-frag lane (gg,rr), rr<8: W2[rr][jsel(gg,i)],
//   jsel(gg,i)= j0 + (i<4 ? gg*4+i : 16+gg*4+(i-4))  — matches the FFN1
//   output fragment order so FFN2's B-operand is lane-local.
// ---------------------------------------------------------------------------
__global__ __launch_bounds__(64) void repack_kernel(Params P, short* ws) {
  const int wg = blockIdx.x;              // 8 layers * 64 blocks
  const int L = wg >> 6, blk = wg & 63;
  const int l = (int)threadIdx.x, gg = l >> 4, rr = l & 15;
  const float *W1p, *b1p, *W2p;
  if (L < 6) { W1p = P.in[7] + L * 16384;  b1p = P.in[8] + L * 2048;  W2p = P.in[9] + L * 16384; }
  else { int m = L - 6; W1p = P.in[25] + m * 16384; b1p = P.in[26] + m * 2048; W2p = P.in[27] + m * 16384; }
  short* out = ws + (L * 64 + blk) * 2048;
  const int j0 = blk * 32;
  short8 z = {0,0,0,0,0,0,0,0};
  for (int tt = 0; tt < 2; ++tt) {
    int j = j0 + tt * 16 + rr;
    short8 r = z;
    if (gg == 3) {
      unsigned short h = f2bf(b1p[j]);
      r[0] = (short)h; r[1] = (short)f2bf(b1p[j] - bf2f(h));
    } else {
      const float* p = W1p + j * 8;
#pragma unroll
      for (int i = 0; i < 8; ++i) {
        float v = p[i];
        unsigned short h = f2bf(v);
        r[i] = (short)((gg == 1) ? f2bf(v - bf2f(h)) : h);
      }
    }
    *(short8*)(out + tt * 512 + l * 8) = r;
  }
  short8 wh = z, wl = z;
  if (rr < 8) {
#pragma unroll
    for (int i = 0; i < 8; ++i) {
      int j = j0 + (i < 4 ? gg * 4 + i : 16 + gg * 4 + (i - 4));
      float v = W2p[rr * 2048 + j];
      unsigned short h = f2bf(v);
      wh[i] = (short)h;
      wl[i] = (short)f2bf(v - bf2f(h));
    }
  }
  *(short8*)(out + 1024 + l * 8) = wh;
  *(short8*)(out + 1536 + l * 8) = wl;
}

// ---------------------------------------------------------------------------
__global__ __launch_bounds__(NT) void tdec_kernel(Params P, const short* ws) {
  const int b    = blockIdx.x;
  const int tid  = (int)threadIdx.x;
  const int lane = tid & 63;
  const int wave = tid >> 6;
  const int gg   = lane >> 4;   // k-group within MFMA
  const int rr   = lane & 15;   // row/col within 16-tile

  __shared__ float buf[T][D];
  __shared__ __align__(16) float X[64][D];   // zero-padded rows >= R
  __shared__ float Mem[64][D];
  __shared__ float Qs[64][D];
  __shared__ float Ks[64][D];
  __shared__ float Vs[64][D];
  __shared__ float ATT[64][D];
  __shared__ __align__(16) float red[NRED * 1024];  // FFN partials 32KB
  __shared__ float wAll[10 * 288];
  __shared__ float lnp[40][D];
  __shared__ float b2all[8][D];
  __shared__ float fcw[SD][D];
  __shared__ float fcbv[SD];
  __shared__ float embw[D][SD];
  __shared__ float embbv[D];
  __shared__ float stv[SD];

  // ---------------- one-time staging of all small weights ----------------
  for (int o = tid; o < 2880; o += NT) {
    int a = o / 288, off = o - a * 288;
    const float *Wq, *Bq, *Wo, *Bo; int li;
    if (a < 6)              { li = a;            Wq=P.in[3];  Bq=P.in[4];  Wo=P.in[5];  Bo=P.in[6];  }
    else if (((a - 6) & 1) == 0) { li = (a-6)>>1; Wq=P.in[17]; Bq=P.in[18]; Wo=P.in[19]; Bo=P.in[20]; }
    else                    { li = (a-6)>>1;     Wq=P.in[21]; Bq=P.in[22]; Wo=P.in[23]; Bo=P.in[24]; }
    float v;
    if (off < 192)      v = Wq[li*192 + off];
    else if (off < 216) v = Bq[li*24  + off - 192];
    else if (off < 280) v = Wo[li*64  + off - 216];
    else                v = Bo[li*8   + off - 280];
    wAll[o] = v;
  }
  for (int o = tid; o < 320; o += NT) {
    int row = o >> 3, k = o & 7;
    const float* src;
    if (row < 24) { int li = row >> 2, w = row & 3;
      src = (w==0 ? P.in[11] : w==1 ? P.in[12] : w==2 ? P.in[13] : P.in[14]) + li*8;
    } else if (row < 26) src = (row == 24 ? P.in[15] : P.in[16]);
    else if (row < 38) { int q = row - 26, li = q / 6, w = q - li*6;
      src = (w==0?P.in[29]:w==1?P.in[30]:w==2?P.in[31]:w==3?P.in[32]:w==4?P.in[33]:P.in[34]) + li*8;
    } else src = (row == 38 ? P.in[35] : P.in[36]);
    lnp[row][k] = src[k];
  }
  if (tid < 64) { int row = tid >> 3, k = tid & 7;
    b2all[row][k] = (row < 6) ? P.in[10][row*8 + k] : P.in[28][(row-6)*8 + k]; }
  if (tid < 136) fcw[tid >> 3][tid & 7] = P.in[37][tid];
  if (tid < SD)  fcbv[tid] = P.in[38][tid];
  if (tid < 136) embw[tid / 17][tid % 17] = P.in[1][tid];
  if (tid < D)   embbv[tid] = P.in[2][tid];
  if (tid < D)   buf[0][tid] = P.in[0][b*D + tid];
  __syncthreads();

  const short8 zero8 = {0,0,0,0,0,0,0,0};
  const floatx4 zf4  = {0.f,0.f,0.f,0.f};

  // ---------------- helpers ----------------
  auto proj8 = [&](float (*dst)[D], const float (*src)[D], const float* w,
                   const float* bias, int R) {
    for (int o = tid; o < (R << 3); o += NT) {
      int r = o >> 3, d = o & 7;
      const float* wr = w + d * 8;
      const float* xr = src[r];
      float s = bias[d];
#pragma unroll
      for (int k = 0; k < 8; ++k) s += xr[k] * wr[k];
      dst[r][d] = s;
    }
  };

  // fixed-shift single-pass softmax (LN-bounded scores; exp(s-10) safe).
  // 8 threads per (p,h) when R<=32, else 4; shfl_xor combine.
  auto attn = [&](int R, bool causal) {
    if (R <= 32) {
      int p = tid >> 5, h2 = ((tid >> 3) & 3) << 1, e = tid & 7;
      if (p < R) {
        float q0 = Qs[p][h2]     * 0.70710678118654752f;
        float q1 = Qs[p][h2 + 1] * 0.70710678118654752f;
        int lim = causal ? p : (R - 1);
        float l = 0.f, a0 = 0.f, a1 = 0.f;
        for (int j = e; j <= lim; j += 8) {
          float s = q0 * Ks[j][h2] + q1 * Ks[j][h2 + 1] - 10.f;
          float ev = __expf(s);
          l += ev; a0 += ev * Vs[j][h2]; a1 += ev * Vs[j][h2 + 1];
        }
        l  += __shfl_xor(l, 1);  l  += __shfl_xor(l, 2);  l  += __shfl_xor(l, 4);
        a0 += __shfl_xor(a0, 1); a0 += __shfl_xor(a0, 2); a0 += __shfl_xor(a0, 4);
        a1 += __shfl_xor(a1, 1); a1 += __shfl_xor(a1, 2); a1 += __shfl_xor(a1, 4);
        if (e == 0) {
          float rl = 1.f / l;
          ATT[p][h2] = a0 * rl; ATT[p][h2 + 1] = a1 * rl;
        }
      }
    } else {
      int p = tid >> 4, h2 = ((tid >> 2) & 3) << 1, e = tid & 3;
      if (p < R) {
        float q0 = Qs[p][h2]     * 0.70710678118654752f;
        float q1 = Qs[p][h2 + 1] * 0.70710678118654752f;
        int lim = causal ? p : (R - 1);
        float l = 0.f, a0 = 0.f, a1 = 0.f;
        for (int j = e; j <= lim; j += 4) {
          float s = q0 * Ks[j][h2] + q1 * Ks[j][h2 + 1] - 10.f;
          float ev = __expf(s);
          l += ev; a0 += ev * Vs[j][h2]; a1 += ev * Vs[j][h2 + 1];
        }
        l  += __shfl_xor(l, 1);  l  += __shfl_xor(l, 2);
        a0 += __shfl_xor(a0, 1); a0 += __shfl_xor(a0, 2);
        a1 += __shfl_xor(a1, 1); a1 += __shfl_xor(a1, 2);
        if (e == 0) {
          float rl = 1.f / l;
          ATT[p][h2] = a0 * rl; ATT[p][h2 + 1] = a1 * rl;
        }
      }
    }
  };

  auto oproj_ln = [&](const float* wo, const float* bo, const float* g,
                      const float* bb, int R) {
    if (tid < R) {
      float o[8];
#pragma unroll
      for (int d = 0; d < 8; ++d) {
        float s = bo[d] + X[tid][d];
#pragma unroll
        for (int k = 0; k < 8; ++k) s += ATT[tid][k] * wo[d * 8 + k];
        o[d] = s;
      }
      float m = 0.f;
#pragma unroll
      for (int k = 0; k < 8; ++k) m += o[k];
      m *= 0.125f;
      float v = 0.f;
#pragma unroll
      for (int k = 0; k < 8; ++k) { float dm = o[k] - m; v += dm * dm; }
      float rs = rsqrtf(v * 0.125f + 1e-5f);
#pragma unroll
      for (int k = 0; k < 8; ++k) X[tid][k] = (o[k] - m) * rs * g[k] + bb[k];
    }
  };

  auto ln_rows = [&](float (*dst)[D], const float (*src)[D], const float* g,
                     const float* bb, int R) {
    if (tid < R) {
      float o[8];
#pragma unroll
      for (int k = 0; k < 8; ++k) o[k] = src[tid][k];
      float m = 0.f;
#pragma unroll
      for (int k = 0; k < 8; ++k) m += o[k];
      m *= 0.125f;
      float v = 0.f;
#pragma unroll
      for (int k = 0; k < 8; ++k) { float dm = o[k] - m; v += dm * dm; }
      float rs = rsqrtf(v * 0.125f + 1e-5f);
#pragma unroll
      for (int k = 0; k < 8; ++k) dst[tid][k] = (o[k] - m) * rs * g[k] + bb[k];
    }
  };

  auto mha = [&](int a, float (*kvsrc)[D], bool causal, int R,
                 const float* g, const float* bb) {
    const float* wq = &wAll[a * 288];
    proj8(Qs, X,     wq +   0, wq + 192, R);
    proj8(Ks, kvsrc, wq +  64, wq + 200, R);
    proj8(Vs, kvsrc, wq + 128, wq + 208, R);
    __syncthreads();
    attn(R, causal);
    __syncthreads();
    oproj_ln(wq + 216, wq + 280, g, bb, R);
    __syncthreads();
  };

  // MHA computing ONLY row t of the output (K/V proj still full R rows).
  auto mha_row = [&](int a, float (*kvsrc)[D], int R, int t,
                     const float* g, const float* bb) {
    const float* wq = &wAll[a * 288];
    proj8(Ks, kvsrc, wq +  64, wq + 200, R);
    proj8(Vs, kvsrc, wq + 128, wq + 208, R);
    if (tid < 8) {                      // Q projection, row t only
      int d = tid;
      const float* wr = wq + d * 8;
      float s = wq[192 + d];
#pragma unroll
      for (int k = 0; k < 8; ++k) s += X[t][k] * wr[k];
      Qs[t][d] = s;
    }
    __syncthreads();
    if (tid < 32) {                     // attention row t: 8-way j-split
      int h2 = (tid >> 3) << 1, e = tid & 7;
      float q0 = Qs[t][h2]     * 0.70710678118654752f;
      float q1 = Qs[t][h2 + 1] * 0.70710678118654752f;
      float l = 0.f, a0 = 0.f, a1 = 0.f;
      for (int j = e; j < R; j += 8) {
        float s = q0 * Ks[j][h2] + q1 * Ks[j][h2 + 1] - 10.f;
        float ev = __expf(s);
        l += ev; a0 += ev * Vs[j][h2]; a1 += ev * Vs[j][h2 + 1];
      }
      l  += __shfl_xor(l, 1);  l  += __shfl_xor(l, 2);  l  += __shfl_xor(l, 4);
      a0 += __shfl_xor(a0, 1); a0 += __shfl_xor(a0, 2); a0 += __shfl_xor(a0, 4);
      a1 += __shfl_xor(a1, 1); a1 += __shfl_xor(a1, 2); a1 += __shfl_xor(a1, 4);
      if (e == 0) {
        float rl = 1.f / l;
        ATT[t][h2] = a0 * rl; ATT[t][h2 + 1] = a1 * rl;
      }
    }
    __syncthreads();
    if (tid == 0) {                     // oproj + residual + LN, row t
      float o[8];
#pragma unroll
      for (int d = 0; d < 8; ++d) {
        float s = wq[280 + d] + X[t][d];
#pragma unroll
        for (int k = 0; k < 8; ++k) s += ATT[t][k] * wq[216 + d * 8 + k];
        o[d] = s;
      }
      float m = 0.f;
#pragma unroll
      for (int k = 0; k < 8; ++k) m += o[k];
      m *= 0.125f;
      float v = 0.f;
#pragma unroll
      for (int k = 0; k < 8; ++k) { float dm = o[k] - m; v += dm * dm; }
      float rs = rsqrtf(v * 0.125f + 1e-5f);
#pragma unroll
      for (int k = 0; k < 8; ++k) X[t][k] = (o[k] - m) * rs * g[k] + bb[k];
    }
    __syncthreads();
  };

  // FFN, swapped-operand form (r5 3-term arithmetic — FROZEN).
  // Two-stage cross-wave reduce: waves 0-7 write red slots, waves 8-15 add.
  auto ffn = [&](const short* wsL, const float* b2, const float* g,
                 const float* bb, int R, int Mt) {
    // issue block-0 fragment loads first; bx-setup VALU hides the latency
    const short* pb = wsL + (wave * BPW) * 2048;
    short8 a0  = *(const short8*)(pb + lane * 8);
    short8 a1  = *(const short8*)(pb + 512 + lane * 8);
    short8 w2h = *(const short8*)(pb + 1024 + lane * 8);
    short8 w2l = *(const short8*)(pb + 1536 + lane * 8);

    // B-frags (X^T) per r-tile; lane variant: gg0/1=x_hi, gg2=x_lo, gg3=ones
    short8 bx[4];
#pragma unroll
    for (int mt = 0; mt < 4; ++mt) {
      short8 v = zero8;
      if (mt < Mt) {
        if (gg == 3) { v[0] = (short)0x3F80; v[1] = (short)0x3F80; }
        else {
          int r = mt * 16 + rr;
          float4 A = *(const float4*)&X[r][0];
          float4 Bv = *(const float4*)&X[r][4];
          unsigned u0 = cvtpk(A.x, A.y), u1 = cvtpk(A.z, A.w);
          unsigned u2 = cvtpk(Bv.x, Bv.y), u3 = cvtpk(Bv.z, Bv.w);
          if (gg == 2) {
            unsigned l0 = cvtpk(A.x - lo2f(u0), A.y - hi2f(u0));
            unsigned l1 = cvtpk(A.z - lo2f(u1), A.w - hi2f(u1));
            unsigned l2 = cvtpk(Bv.x - lo2f(u2), Bv.y - hi2f(u2));
            unsigned l3 = cvtpk(Bv.z - lo2f(u3), Bv.w - hi2f(u3));
            v = pack4(l0, l1, l2, l3);
          } else {
            v = pack4(u0, u1, u2, u3);
          }
        }
      }
      bx[mt] = v;
    }

    floatx4 acc[4] = {zf4, zf4, zf4, zf4};
    for (int blkI = 0; blkI < BPW; ++blkI) {
      short8 na0 = zero8, na1 = zero8, nw2h = zero8, nw2l = zero8;
      if (blkI + 1 < BPW) {            // prefetch next block's fragments
        const short* pn = pb + (blkI + 1) * 2048;
        na0  = *(const short8*)(pn + lane * 8);
        na1  = *(const short8*)(pn + 512 + lane * 8);
        nw2h = *(const short8*)(pn + 1024 + lane * 8);
        nw2l = *(const short8*)(pn + 1536 + lane * 8);
      }
#pragma unroll
      for (int mt = 0; mt < 4; ++mt) {
        if (mt < Mt) {
          floatx4 h0 = mfma16(a0, bx[mt], zf4);   // rows j0..j0+15, cols=pos
          floatx4 h1 = mfma16(a1, bx[mt], zf4);   // rows j0+16..j0+31
          float v0 = fmaxf(h0[0], 0.f), v1 = fmaxf(h0[1], 0.f);
          float v2 = fmaxf(h0[2], 0.f), v3 = fmaxf(h0[3], 0.f);
          float v4 = fmaxf(h1[0], 0.f), v5 = fmaxf(h1[1], 0.f);
          float v6 = fmaxf(h1[2], 0.f), v7 = fmaxf(h1[3], 0.f);
          unsigned u0 = cvtpk(v0, v1), u1 = cvtpk(v2, v3);
          unsigned u2 = cvtpk(v4, v5), u3 = cvtpk(v6, v7);
          unsigned l0 = cvtpk(v0 - lo2f(u0), v1 - hi2f(u0));
          unsigned l1 = cvtpk(v2 - lo2f(u1), v3 - hi2f(u1));
          unsigned l2 = cvtpk(v4 - lo2f(u2), v5 - hi2f(u2));
          unsigned l3 = cvtpk(v6 - lo2f(u3), v7 - hi2f(u3));
          short8 ah = pack4(u0, u1, u2, u3);
          short8 al = pack4(l0, l1, l2, l3);
          // A-operand = W2 (rows = d), B-operand = h (cols = pos):
          // D[row=d][col=pos] matches the reduce below.
          acc[mt] = mfma16(w2h, ah, acc[mt]);
          acc[mt] = mfma16(w2h, al, acc[mt]);
          acc[mt] = mfma16(w2l, ah, acc[mt]);
        }
      }
      a0 = na0; a1 = na1; w2h = nw2h; w2l = nw2l;
    }

    // two-stage cross-wave reduce + residual + bias + LN
    if (wave < 8) {
#pragma unroll
      for (int mt = 0; mt < 4; ++mt)
        if (mt < Mt)
          *(floatx4*)&red[(((wave << 2) + mt) << 8) + (lane << 2)] = acc[mt];
    }
    __syncthreads();
    if (wave >= 8) {
#pragma unroll
      for (int mt = 0; mt < 4; ++mt)
        if (mt < Mt) {
          float* p = &red[((((wave - 8) << 2) + mt) << 8) + (lane << 2)];
          floatx4 cur = *(floatx4*)p;
          *(floatx4*)p = cur + acc[mt];
        }
    }
    __syncthreads();
    if (tid < R) {
      int r = tid, mt = r >> 4, rl = r & 15;
      float o[8];
#pragma unroll
      for (int d = 0; d < 8; ++d) {
        float s = X[r][d] + b2[d];
        // acc layout: lane (gg=d>>2, rr=rl) reg (d&3) holds out^T[d][mt*16+rl]
        int base = (mt << 8) + ((((d >> 2) << 4) + rl) << 2) + (d & 3);
#pragma unroll
        for (int w = 0; w < NRED; ++w) s += red[(w << 10) + base];
        o[d] = s;
      }
      float m = 0.f;
#pragma unroll
      for (int k = 0; k < 8; ++k) m += o[k];
      m *= 0.125f;
      float var = 0.f;
#pragma unroll
      for (int k = 0; k < 8; ++k) { float dm = o[k] - m; var += dm * dm; }
      float rs = rsqrtf(var * 0.125f + 1e-5f);
#pragma unroll
      for (int k = 0; k < 8; ++k) X[r][k] = (o[k] - m) * rs * g[k] + bb[k];
    }
    __syncthreads();
  };

  // FFN computing ONLY row t (column 0 of tile 0; k-sum column-independent
  // so the row-t result is bit-identical to full ffn). Two-stage reduce.
  auto ffn_row = [&](const short* wsL, const float* b2, const float* g,
                     const float* bb, int t) {
    const short* pb = wsL + (wave * BPW) * 2048;
    short8 a0  = *(const short8*)(pb + lane * 8);
    short8 a1  = *(const short8*)(pb + 512 + lane * 8);
    short8 w2h = *(const short8*)(pb + 1024 + lane * 8);
    short8 w2l = *(const short8*)(pb + 1536 + lane * 8);

    short8 bx = zero8;
    if (gg == 3) { bx[0] = (short)0x3F80; bx[1] = (short)0x3F80; }
    else if (rr == 0) {
      float4 A = *(const float4*)&X[t][0];
      float4 Bv = *(const float4*)&X[t][4];
      unsigned u0 = cvtpk(A.x, A.y), u1 = cvtpk(A.z, A.w);
      unsigned u2 = cvtpk(Bv.x, Bv.y), u3 = cvtpk(Bv.z, Bv.w);
      if (gg == 2) {
        unsigned l0 = cvtpk(A.x - lo2f(u0), A.y - hi2f(u0));
        unsigned l1 = cvtpk(A.z - lo2f(u1), A.w - hi2f(u1));
        unsigned l2 = cvtpk(Bv.x - lo2f(u2), Bv.y - hi2f(u2));
        unsigned l3 = cvtpk(Bv.z - lo2f(u3), Bv.w - hi2f(u3));
        bx = pack4(l0, l1, l2, l3);
      } else {
        bx = pack4(u0, u1, u2, u3);
      }
    }

    floatx4 acc = zf4;
    for (int blkI = 0; blkI < BPW; ++blkI) {
      short8 na0 = zero8, na1 = zero8, nw2h = zero8, nw2l = zero8;
      if (blkI + 1 < BPW) {
        const short* pn = pb + (blkI + 1) * 2048;
        na0  = *(const short8*)(pn + lane * 8);
        na1  = *(const short8*)(pn + 512 + lane * 8);
        nw2h = *(const short8*)(pn + 1024 + lane * 8);
        nw2l = *(const short8*)(pn + 1536 + lane * 8);
      }
      floatx4 h0 = mfma16(a0, bx, zf4);
      floatx4 h1 = mfma16(a1, bx, zf4);
      float v0 = fmaxf(h0[0], 0.f), v1 = fmaxf(h0[1], 0.f);
      float v2 = fmaxf(h0[2], 0.f), v3 = fmaxf(h0[3], 0.f);
      float v4 = fmaxf(h1[0], 0.f), v5 = fmaxf(h1[1], 0.f);
      float v6 = fmaxf(h1[2], 0.f), v7 = fmaxf(h1[3], 0.f);
      unsigned u0 = cvtpk(v0, v1), u1 = cvtpk(v2, v3);
      unsigned u2 = cvtpk(v4, v5), u3 = cvtpk(v6, v7);
      unsigned l0 = cvtpk(v0 - lo2f(u0), v1 - hi2f(u0));
      unsigned l1 = cvtpk(v2 - lo2f(u1), v3 - hi2f(u1));
      unsigned l2 = cvtpk(v4 - lo2f(u2), v5 - hi2f(u2));
      unsigned l3 = cvtpk(v6 - lo2f(u3), v7 - hi2f(u3));
      short8 ah = pack4(u0, u1, u2, u3);
      short8 al = pack4(l0, l1, l2, l3);
      acc = mfma16(w2h, ah, acc);
      acc = mfma16(w2h, al, acc);
      acc = mfma16(w2l, ah, acc);
      a0 = na0; a1 = na1; w2h = nw2h; w2l = nw2l;
    }

    if (wave < 8)
      *(floatx4*)&red[(wave << 10) + (lane << 2)] = acc;
    __syncthreads();
    if (wave >= 8) {
      float* p = &red[((wave - 8) << 10) + (lane << 2)];
      floatx4 cur = *(floatx4*)p;
      *(floatx4*)p = cur + acc;
    }
    __syncthreads();
    if (tid == 0) {
      float o[8];
#pragma unroll
      for (int d = 0; d < 8; ++d) {
        float s = X[t][d] + b2[d];
        int base = ((d >> 2) << 6) + (d & 3);   // lane (gg=d>>2, rr=0) reg d&3
#pragma unroll
        for (int w = 0; w < NRED; ++w) s += red[(w << 10) + base];
        o[d] = s;
      }
      float m = 0.f;
#pragma unroll
      for (int k = 0; k < 8; ++k) m += o[k];
      m *= 0.125f;
      float var = 0.f;
#pragma unroll
      for (int k = 0; k < 8; ++k) { float dm = o[k] - m; var += dm * dm; }
      float rs = rsqrtf(var * 0.125f + 1e-5f);
#pragma unroll
      for (int k = 0; k < 8; ++k) X[t][k] = (o[k] - m) * rs * g[k] + bb[k];
    }
    __syncthreads();
  };

  // ---------------- the 60-step scan ----------------
  for (int t = 0; t < T; ++t) {
    const int R = t + 1;
    const int Mt = (R + 15) >> 4;

    for (int o = tid; o < 512; o += NT) {
      int r = o >> 3, d = o & 7;
      X[r][d] = (r < R) ? buf[r][d] : 0.f;
    }
    __syncthreads();

    // encoder: 6 layers, keys <= t
    for (int li = 0; li < 6; ++li) {
      mha(li, X, false, R, lnp[li * 4 + 0], lnp[li * 4 + 1]);
      ffn(ws + li * LSTR, b2all[li], lnp[li * 4 + 2], lnp[li * 4 + 3], R, Mt);
    }
    ln_rows(X, X, lnp[24], lnp[25], R);
    __syncthreads();
    for (int o = tid; o < 512; o += NT) {
      int r = o >> 3, d = o & 7;
      if (r < R) Mem[r][d] = X[r][d];
      X[r][d] = (r < R) ? buf[r][d] : 0.f;
    }
    __syncthreads();

    // decoder layer 1: full (its rows are layer-2 self-attn keys)
    mha(6, X,   true,  R, lnp[26], lnp[27]);
    mha(7, Mem, false, R, lnp[28], lnp[29]);
    ffn(ws + 6 * LSTR, b2all[6], lnp[30], lnp[31], R, Mt);

    // decoder layer 2: ONLY row t is ever consumed downstream
    mha_row(8, X,   R, t, lnp[32], lnp[33]);
    mha_row(9, Mem, R, t, lnp[34], lnp[35]);
    ffn_row(ws + 7 * LSTR, b2all[7], lnp[36], lnp[37], t);

    // final LN (row t) + st = y[t] @ fc_W^T + fc_b -> out; embed to buf[t+1]
    if (tid == 0) {
      float o[8];
#pragma unroll
      for (int k = 0; k < 8; ++k) o[k] = X[t][k];
      float m = 0.f;
#pragma unroll
      for (int k = 0; k < 8; ++k) m += o[k];
      m *= 0.125f;
      float v = 0.f;
#pragma unroll
      for (int k = 0; k < 8; ++k) { float dm = o[k] - m; v += dm * dm; }
      float rs = rsqrtf(v * 0.125f + 1e-5f);
#pragma unroll
      for (int k = 0; k < 8; ++k) X[t][k] = (o[k] - m) * rs * lnp[38][k] + lnp[39][k];
    }
    __syncthreads();
    if (tid < SD) {
      float s = fcbv[tid];
#pragma unroll
      for (int k = 0; k < 8; ++k) s += X[t][k] * fcw[tid][k];
      stv[tid] = s;
      P.out[(b * T + t) * SD + tid] = s;
    }
    __syncthreads();
    if (t + 1 < T && tid < D) {
      float s = embbv[tid];
#pragma unroll
      for (int k = 0; k < SD; ++k) s += stv[k] * embw[tid][k];
      buf[t + 1][tid] = s;
    }
    __syncthreads();
  }
}

extern "C" void kernel_launch(void* const* d_in, const int* in_sizes, int n_in,
                              void* d_out, int out_size, void* d_ws, size_t ws_size,
                              hipStream_t stream) {
  (void)in_sizes; (void)n_in; (void)ws_size; (void)out_size;
  Params P;
  for (int i = 0; i < 39; ++i) P.in[i] = (const float*)d_in[i];
  P.out = (float*)d_out;
  short* ws = (short*)d_ws;   // 8 layers * 256KB = 2MB of packed fragments
  repack_kernel<<<dim3(8 * NBLK), dim3(64), 0, stream>>>(P, ws);
  tdec_kernel<<<dim3(128), dim3(NT), 0, stream>>>(P, ws);
}

// Round 13
// 3591.659 us; speedup vs baseline: 1.0514x; 1.0514x over previous
//
#include <hip/hip_runtime.h>

// TransformerDecoder scan: B=128 independent sequences, one workgroup each,
// 8 waves/WG (NT=512 — r12 proved 16 waves is issue-neutral and L2-thrashes).
// Round-13: r10 base (3473us best) + FFN fragment preload under oproj_ln +
// depth-2 block prefetch (the two unrefuted r6 mechanisms, now WITHOUT the
// poisonous shfl-epilogues). FFN 3-term hi/lo arithmetic, repack, row-t
// decoder specialization: FROZEN (h-lo term load-bearing; scan amplifies
// ~x800 — r9). Single-thread-per-row epilogues (r6 shfl variant regressed).

typedef __attribute__((ext_vector_type(8))) short short8;
typedef __attribute__((ext_vector_type(4))) float floatx4;
typedef __attribute__((ext_vector_type(4))) unsigned uint4v;

#define DEV static __device__ __forceinline__

namespace {
constexpr int D   = 8;
constexpr int T   = 60;
constexpr int DFF = 2048;
constexpr int SD  = 17;
constexpr int NT  = 512;             // 8 waves
constexpr int NW  = NT / 64;
constexpr int NBLK = DFF / 32;       // 64 blocks of 32 hidden cols
constexpr int BPW  = NBLK / NW;      // 8 blocks per wave
constexpr int LSTR = NBLK * 2048;    // shorts per layer in ws (256KB)
}

struct Params { const float* in[39]; float* out; };

// fp32 -> bf16 (round-half-up) — repack-time only
DEV unsigned short f2bf(float f) {
  unsigned u = __builtin_bit_cast(unsigned, f);
  return (unsigned short)((u + 0x8000u) >> 16);
}
DEV float bf2f(unsigned short h) {
  unsigned u = ((unsigned)h) << 16;
  return __builtin_bit_cast(float, u);
}
DEV floatx4 mfma16(short8 a, short8 b, floatx4 c) {
  return __builtin_amdgcn_mfma_f32_16x16x32_bf16(a, b, c, 0, 0, 0);
}
// packed fp32->bf16 (RTNE), 2 values -> 1 dword. No builtin on gfx950.
DEV unsigned cvtpk(float lo, float hi) {
  unsigned r;
  asm("v_cvt_pk_bf16_f32 %0, %1, %2" : "=v"(r) : "v"(lo), "v"(hi));
  return r;
}
DEV float lo2f(unsigned u) { return __builtin_bit_cast(float, u << 16); }
DEV float hi2f(unsigned u) { return __builtin_bit_cast(float, u & 0xffff0000u); }
DEV short8 pack4(unsigned a, unsigned b, unsigned c, unsigned d) {
  uint4v u = {a, b, c, d};
  return __builtin_bit_cast(short8, u);
}

// ---------------------------------------------------------------------------
// Repack kernel: per (layer L, 32-hidden block blk) write 2048 shorts:
//   [0:512) W1 A-frag tile 2*blk | [512:1024) tile 2*blk+1
//   [1024:1536) W2 A-frag hi     | [1536:2048) W2 A-frag lo
// W1 A-frag lane (gg,rr): gg0=hi(W1[j0+rr][0..7]) gg1=lo gg2=hi(dup)
//                         gg3={b1_hi,b1_lo,0..} (bias folded, B supplies 1.0)
// W2 A-frag lane (gg,rr), rr<8: W2[rr][jsel(gg,i)],
//   jsel(gg,i)= j0 + (i<4 ? gg*4+i : 16+gg*4+(i-4))  — matches the FFN1
//   output fragment order so FFN2's B-operand is lane-local.
// ---------------------------------------------------------------------------
__global__ __launch_bounds__(64) void repack_kernel(Params P, short* ws) {
  const int wg = blockIdx.x;              // 8 layers * 64 blocks
  const int L = wg >> 6, blk = wg & 63;
  const int l = (int)threadIdx.x, gg = l >> 4, rr = l & 15;
  const float *W1p, *b1p, *W2p;
  if (L < 6) { W1p = P.in[7] + L * 16384;  b1p = P.in[8] + L * 2048;  W2p = P.in[9] + L * 16384; }
  else { int m = L - 6; W1p = P.in[25] + m * 16384; b1p = P.in[26] + m * 2048; W2p = P.in[27] + m * 16384; }
  short* out = ws + (L * 64 + blk) * 2048;
  const int j0 = blk * 32;
  short8 z = {0,0,0,0,0,0,0,0};
  for (int tt = 0; tt < 2; ++tt) {
    int j = j0 + tt * 16 + rr;
    short8 r = z;
    if (gg == 3) {
      unsigned short h = f2bf(b1p[j]);
      r[0] = (short)h; r[1] = (short)f2bf(b1p[j] - bf2f(h));
    } else {
      const float* p = W1p + j * 8;
#pragma unroll
      for (int i = 0; i < 8; ++i) {
        float v = p[i];
        unsigned short h = f2bf(v);
        r[i] = (short)((gg == 1) ? f2bf(v - bf2f(h)) : h);
      }
    }
    *(short8*)(out + tt * 512 + l * 8) = r;
  }
  short8 wh = z, wl = z;
  if (rr < 8) {
#pragma unroll
    for (int i = 0; i < 8; ++i) {
      int j = j0 + (i < 4 ? gg * 4 + i : 16 + gg * 4 + (i - 4));
      float v = W2p[rr * 2048 + j];
      unsigned short h = f2bf(v);
      wh[i] = (short)h;
      wl[i] = (short)f2bf(v - bf2f(h));
    }
  }
  *(short8*)(out + 1024 + l * 8) = wh;
  *(short8*)(out + 1536 + l * 8) = wl;
}

struct FragBlk { short8 a0, a1, w2h, w2l; };

// ---------------------------------------------------------------------------
__global__ __launch_bounds__(NT, 2) void tdec_kernel(Params P, const short* ws) {
  const int b    = blockIdx.x;
  const int tid  = (int)threadIdx.x;
  const int lane = tid & 63;
  const int wave = tid >> 6;
  const int gg   = lane >> 4;   // k-group within MFMA
  const int rr   = lane & 15;   // row/col within 16-tile

  __shared__ float buf[T][D];
  __shared__ __align__(16) float X[64][D];   // zero-padded rows >= R
  __shared__ float Mem[64][D];
  __shared__ float Qs[64][D];
  __shared__ float Ks[64][D];
  __shared__ float Vs[64][D];
  __shared__ float ATT[64][D];
  __shared__ __align__(16) float red[NW * 1024];  // FFN cross-wave partials 32KB
  __shared__ float wAll[10 * 288];
  __shared__ float lnp[40][D];
  __shared__ float b2all[8][D];
  __shared__ float fcw[SD][D];
  __shared__ float fcbv[SD];
  __shared__ float embw[D][SD];
  __shared__ float embbv[D];
  __shared__ float stv[SD];

  // ---------------- one-time staging of all small weights ----------------
  for (int o = tid; o < 2880; o += NT) {
    int a = o / 288, off = o - a * 288;
    const float *Wq, *Bq, *Wo, *Bo; int li;
    if (a < 6)              { li = a;            Wq=P.in[3];  Bq=P.in[4];  Wo=P.in[5];  Bo=P.in[6];  }
    else if (((a - 6) & 1) == 0) { li = (a-6)>>1; Wq=P.in[17]; Bq=P.in[18]; Wo=P.in[19]; Bo=P.in[20]; }
    else                    { li = (a-6)>>1;     Wq=P.in[21]; Bq=P.in[22]; Wo=P.in[23]; Bo=P.in[24]; }
    float v;
    if (off < 192)      v = Wq[li*192 + off];
    else if (off < 216) v = Bq[li*24  + off - 192];
    else if (off < 280) v = Wo[li*64  + off - 216];
    else                v = Bo[li*8   + off - 280];
    wAll[o] = v;
  }
  for (int o = tid; o < 320; o += NT) {
    int row = o >> 3, k = o & 7;
    const float* src;
    if (row < 24) { int li = row >> 2, w = row & 3;
      src = (w==0 ? P.in[11] : w==1 ? P.in[12] : w==2 ? P.in[13] : P.in[14]) + li*8;
    } else if (row < 26) src = (row == 24 ? P.in[15] : P.in[16]);
    else if (row < 38) { int q = row - 26, li = q / 6, w = q - li*6;
      src = (w==0?P.in[29]:w==1?P.in[30]:w==2?P.in[31]:w==3?P.in[32]:w==4?P.in[33]:P.in[34]) + li*8;
    } else src = (row == 38 ? P.in[35] : P.in[36]);
    lnp[row][k] = src[k];
  }
  if (tid < 64) { int row = tid >> 3, k = tid & 7;
    b2all[row][k] = (row < 6) ? P.in[10][row*8 + k] : P.in[28][(row-6)*8 + k]; }
  if (tid < 136) fcw[tid >> 3][tid & 7] = P.in[37][tid];
  if (tid < SD)  fcbv[tid] = P.in[38][tid];
  if (tid < 136) embw[tid / 17][tid % 17] = P.in[1][tid];
  if (tid < D)   embbv[tid] = P.in[2][tid];
  if (tid < D)   buf[0][tid] = P.in[0][b*D + tid];
  __syncthreads();

  const short8 zero8 = {0,0,0,0,0,0,0,0};
  const floatx4 zf4  = {0.f,0.f,0.f,0.f};

  // ---------------- helpers ----------------
  auto ldblk = [&](const short* pb) -> FragBlk {
    FragBlk f;
    f.a0  = *(const short8*)(pb + lane * 8);
    f.a1  = *(const short8*)(pb + 512 + lane * 8);
    f.w2h = *(const short8*)(pb + 1024 + lane * 8);
    f.w2l = *(const short8*)(pb + 1536 + lane * 8);
    return f;
  };

  auto proj8 = [&](float (*dst)[D], const float (*src)[D], const float* w,
                   const float* bias, int R) {
    for (int o = tid; o < (R << 3); o += NT) {
      int r = o >> 3, d = o & 7;
      const float* wr = w + d * 8;
      const float* xr = src[r];
      float s = bias[d];
#pragma unroll
      for (int k = 0; k < 8; ++k) s += xr[k] * wr[k];
      dst[r][d] = s;
    }
  };

  // fixed-shift single-pass softmax (LN-bounded scores; exp(s-10) safe).
  // 4 threads per (p,h) when R<=32, else 2; shfl_xor combine.
  auto attn = [&](int R, bool causal) {
    if (R <= 32) {
      int p = tid >> 4, h2 = ((tid >> 2) & 3) << 1, e = tid & 3;
      if (p < R) {
        float q0 = Qs[p][h2]     * 0.70710678118654752f;
        float q1 = Qs[p][h2 + 1] * 0.70710678118654752f;
        int lim = causal ? p : (R - 1);
        float l = 0.f, a0 = 0.f, a1 = 0.f;
        for (int j = e; j <= lim; j += 4) {
          float s = q0 * Ks[j][h2] + q1 * Ks[j][h2 + 1] - 10.f;
          float ev = __expf(s);
          l += ev; a0 += ev * Vs[j][h2]; a1 += ev * Vs[j][h2 + 1];
        }
        l  += __shfl_xor(l, 1);  l  += __shfl_xor(l, 2);
        a0 += __shfl_xor(a0, 1); a0 += __shfl_xor(a0, 2);
        a1 += __shfl_xor(a1, 1); a1 += __shfl_xor(a1, 2);
        if (e == 0) {
          float rl = 1.f / l;
          ATT[p][h2] = a0 * rl; ATT[p][h2 + 1] = a1 * rl;
        }
      }
    } else {
      int p = tid >> 3, h2 = ((tid >> 1) & 3) << 1, e = tid & 1;
      if (p < R) {
        float q0 = Qs[p][h2]     * 0.70710678118654752f;
        float q1 = Qs[p][h2 + 1] * 0.70710678118654752f;
        int lim = causal ? p : (R - 1);
        float l = 0.f, a0 = 0.f, a1 = 0.f;
        for (int j = e; j <= lim; j += 2) {
          float s = q0 * Ks[j][h2] + q1 * Ks[j][h2 + 1] - 10.f;
          float ev = __expf(s);
          l += ev; a0 += ev * Vs[j][h2]; a1 += ev * Vs[j][h2 + 1];
        }
        l  += __shfl_xor(l, 1);
        a0 += __shfl_xor(a0, 1);
        a1 += __shfl_xor(a1, 1);
        if (e == 0) {
          float rl = 1.f / l;
          ATT[p][h2] = a0 * rl; ATT[p][h2 + 1] = a1 * rl;
        }
      }
    }
  };

  // out-projection + residual + LN, one thread per row (r10-validated form).
  // Caller must __syncthreads() afterwards.
  auto oproj_ln = [&](const float* wq, const float* g, const float* bb, int R) {
    if (tid < R) {
      const float* wo = wq + 216;
      float o[8];
#pragma unroll
      for (int d = 0; d < 8; ++d) {
        float s = wq[280 + d] + X[tid][d];
#pragma unroll
        for (int k = 0; k < 8; ++k) s += ATT[tid][k] * wo[d * 8 + k];
        o[d] = s;
      }
      float m = 0.f;
#pragma unroll
      for (int k = 0; k < 8; ++k) m += o[k];
      m *= 0.125f;
      float v = 0.f;
#pragma unroll
      for (int k = 0; k < 8; ++k) { float dm = o[k] - m; v += dm * dm; }
      float rs = rsqrtf(v * 0.125f + 1e-5f);
#pragma unroll
      for (int k = 0; k < 8; ++k) X[tid][k] = (o[k] - m) * rs * g[k] + bb[k];
    }
  };

  auto ln_rows = [&](float (*dst)[D], const float (*src)[D], const float* g,
                     const float* bb, int R) {
    if (tid < R) {
      float o[8];
#pragma unroll
      for (int k = 0; k < 8; ++k) o[k] = src[tid][k];
      float m = 0.f;
#pragma unroll
      for (int k = 0; k < 8; ++k) m += o[k];
      m *= 0.125f;
      float v = 0.f;
#pragma unroll
      for (int k = 0; k < 8; ++k) { float dm = o[k] - m; v += dm * dm; }
      float rs = rsqrtf(v * 0.125f + 1e-5f);
#pragma unroll
      for (int k = 0; k < 8; ++k) dst[tid][k] = (o[k] - m) * rs * g[k] + bb[k];
    }
  };

  // qkv projections + attention (result in ATT); barriers inside.
  auto mha_qa = [&](int a, float (*kvsrc)[D], bool causal, int R) {
    const float* wq = &wAll[a * 288];
    proj8(Qs, X,     wq +   0, wq + 192, R);
    proj8(Ks, kvsrc, wq +  64, wq + 200, R);
    proj8(Vs, kvsrc, wq + 128, wq + 208, R);
    __syncthreads();
    attn(R, causal);
    __syncthreads();
  };

  auto mha = [&](int a, float (*kvsrc)[D], bool causal, int R,
                 const float* g, const float* bb) {
    mha_qa(a, kvsrc, causal, R);
    oproj_ln(&wAll[a * 288], g, bb, R);
    __syncthreads();
  };

  // K/V proj + row-t Q + row-t attention (no oproj); barriers inside.
  auto mha_row_qa = [&](int a, float (*kvsrc)[D], int R, int t) {
    const float* wq = &wAll[a * 288];
    proj8(Ks, kvsrc, wq +  64, wq + 200, R);
    proj8(Vs, kvsrc, wq + 128, wq + 208, R);
    if (tid < 8) {                      // Q projection, row t only
      int d = tid;
      const float* wr = wq + d * 8;
      float s = wq[192 + d];
#pragma unroll
      for (int k = 0; k < 8; ++k) s += X[t][k] * wr[k];
      Qs[t][d] = s;
    }
    __syncthreads();
    if (tid < 32) {                     // attention row t: 8-way j-split
      int h2 = (tid >> 3) << 1, e = tid & 7;
      float q0 = Qs[t][h2]     * 0.70710678118654752f;
      float q1 = Qs[t][h2 + 1] * 0.70710678118654752f;
      float l = 0.f, a0 = 0.f, a1 = 0.f;
      for (int j = e; j < R; j += 8) {
        float s = q0 * Ks[j][h2] + q1 * Ks[j][h2 + 1] - 10.f;
        float ev = __expf(s);
        l += ev; a0 += ev * Vs[j][h2]; a1 += ev * Vs[j][h2 + 1];
      }
      l  += __shfl_xor(l, 1);  l  += __shfl_xor(l, 2);  l  += __shfl_xor(l, 4);
      a0 += __shfl_xor(a0, 1); a0 += __shfl_xor(a0, 2); a0 += __shfl_xor(a0, 4);
      a1 += __shfl_xor(a1, 1); a1 += __shfl_xor(a1, 2); a1 += __shfl_xor(a1, 4);
      if (e == 0) {
        float rl = 1.f / l;
        ATT[t][h2] = a0 * rl; ATT[t][h2 + 1] = a1 * rl;
      }
    }
    __syncthreads();
  };

  // row-t oproj + residual + LN. Caller syncs afterwards.
  auto oproj_row = [&](const float* wq, const float* g, const float* bb, int t) {
    if (tid == 0) {
      float o[8];
#pragma unroll
      for (int d = 0; d < 8; ++d) {
        float s = wq[280 + d] + X[t][d];
#pragma unroll
        for (int k = 0; k < 8; ++k) s += ATT[t][k] * wq[216 + d * 8 + k];
        o[d] = s;
      }
      float m = 0.f;
#pragma unroll
      for (int k = 0; k < 8; ++k) m += o[k];
      m *= 0.125f;
      float v = 0.f;
#pragma unroll
      for (int k = 0; k < 8; ++k) { float dm = o[k] - m; v += dm * dm; }
      float rs = rsqrtf(v * 0.125f + 1e-5f);
#pragma unroll
      for (int k = 0; k < 8; ++k) X[t][k] = (o[k] - m) * rs * g[k] + bb[k];
    }
  };

  auto mha_row = [&](int a, float (*kvsrc)[D], int R, int t,
                     const float* g, const float* bb) {
    mha_row_qa(a, kvsrc, R, t);
    oproj_row(&wAll[a * 288], g, bb, t);
    __syncthreads();
  };

  // FFN, swapped-operand form (r5 3-term arithmetic — FROZEN).
  // f0,f1 = blocks 0,1 preloaded by caller (latency hidden under oproj_ln);
  // depth-2 rotating prefetch inside.
  auto ffn = [&](FragBlk f0, FragBlk f1, const short* pbw, const float* b2,
                 const float* g, const float* bb, int R, int Mt) {
    // B-frags (X^T) per r-tile; lane variant: gg0/1=x_hi, gg2=x_lo, gg3=ones
    short8 bx[4];
#pragma unroll
    for (int mt = 0; mt < 4; ++mt) {
      short8 v = zero8;
      if (mt < Mt) {
        if (gg == 3) { v[0] = (short)0x3F80; v[1] = (short)0x3F80; }
        else {
          int r = mt * 16 + rr;
          float4 A = *(const float4*)&X[r][0];
          float4 Bv = *(const float4*)&X[r][4];
          unsigned u0 = cvtpk(A.x, A.y), u1 = cvtpk(A.z, A.w);
          unsigned u2 = cvtpk(Bv.x, Bv.y), u3 = cvtpk(Bv.z, Bv.w);
          if (gg == 2) {
            unsigned l0 = cvtpk(A.x - lo2f(u0), A.y - hi2f(u0));
            unsigned l1 = cvtpk(A.z - lo2f(u1), A.w - hi2f(u1));
            unsigned l2 = cvtpk(Bv.x - lo2f(u2), Bv.y - hi2f(u2));
            unsigned l3 = cvtpk(Bv.z - lo2f(u3), Bv.w - hi2f(u3));
            v = pack4(l0, l1, l2, l3);
          } else {
            v = pack4(u0, u1, u2, u3);
          }
        }
      }
      bx[mt] = v;
    }

    floatx4 acc[4] = {zf4, zf4, zf4, zf4};
    for (int blkI = 0; blkI < BPW; ++blkI) {
      FragBlk f2 = f1;
      if (blkI + 2 < BPW) f2 = ldblk(pbw + (blkI + 2) * 2048);
#pragma unroll
      for (int mt = 0; mt < 4; ++mt) {
        if (mt < Mt) {
          floatx4 h0 = mfma16(f0.a0, bx[mt], zf4);  // rows j0..j0+15, cols=pos
          floatx4 h1 = mfma16(f0.a1, bx[mt], zf4);  // rows j0+16..j0+31
          float v0 = fmaxf(h0[0], 0.f), v1 = fmaxf(h0[1], 0.f);
          float v2 = fmaxf(h0[2], 0.f), v3 = fmaxf(h0[3], 0.f);
          float v4 = fmaxf(h1[0], 0.f), v5 = fmaxf(h1[1], 0.f);
          float v6 = fmaxf(h1[2], 0.f), v7 = fmaxf(h1[3], 0.f);
          unsigned u0 = cvtpk(v0, v1), u1 = cvtpk(v2, v3);
          unsigned u2 = cvtpk(v4, v5), u3 = cvtpk(v6, v7);
          unsigned l0 = cvtpk(v0 - lo2f(u0), v1 - hi2f(u0));
          unsigned l1 = cvtpk(v2 - lo2f(u1), v3 - hi2f(u1));
          unsigned l2 = cvtpk(v4 - lo2f(u2), v5 - hi2f(u2));
          unsigned l3 = cvtpk(v6 - lo2f(u3), v7 - hi2f(u3));
          short8 ah = pack4(u0, u1, u2, u3);
          short8 al = pack4(l0, l1, l2, l3);
          // A-operand = W2 (rows = d), B-operand = h (cols = pos):
          // D[row=d][col=pos] matches the reduce below.
          acc[mt] = mfma16(f0.w2h, ah, acc[mt]);
          acc[mt] = mfma16(f0.w2h, al, acc[mt]);
          acc[mt] = mfma16(f0.w2l, ah, acc[mt]);
        }
      }
      f0 = f1; f1 = f2;
    }

    // cross-wave reduce + residual + bias + LN, fused per row
#pragma unroll
    for (int mt = 0; mt < 4; ++mt)
      if (mt < Mt)
        *(floatx4*)&red[(((wave << 2) + mt) << 8) + (lane << 2)] = acc[mt];
    __syncthreads();
    if (tid < R) {
      int r = tid, mt = r >> 4, rl = r & 15;
      float o[8];
#pragma unroll
      for (int d = 0; d < 8; ++d) {
        float s = X[r][d] + b2[d];
        // acc layout: lane (gg=d>>2, rr=rl) reg (d&3) holds out^T[d][mt*16+rl]
        int base = (mt << 8) + ((((d >> 2) << 4) + rl) << 2) + (d & 3);
#pragma unroll
        for (int w = 0; w < NW; ++w) s += red[(w << 10) + base];
        o[d] = s;
      }
      float m = 0.f;
#pragma unroll
      for (int k = 0; k < 8; ++k) m += o[k];
      m *= 0.125f;
      float var = 0.f;
#pragma unroll
      for (int k = 0; k < 8; ++k) { float dm = o[k] - m; var += dm * dm; }
      float rs = rsqrtf(var * 0.125f + 1e-5f);
#pragma unroll
      for (int k = 0; k < 8; ++k) X[r][k] = (o[k] - m) * rs * g[k] + bb[k];
    }
    __syncthreads();
  };

  // FFN computing ONLY row t (column 0 of tile 0; k-sum column-independent
  // so the row-t result is bit-identical to full ffn). Same preload scheme.
  auto ffn_row = [&](FragBlk f0, FragBlk f1, const short* pbw, const float* b2,
                     const float* g, const float* bb, int t) {
    short8 bx = zero8;
    if (gg == 3) { bx[0] = (short)0x3F80; bx[1] = (short)0x3F80; }
    else if (rr == 0) {
      float4 A = *(const float4*)&X[t][0];
      float4 Bv = *(const float4*)&X[t][4];
      unsigned u0 = cvtpk(A.x, A.y), u1 = cvtpk(A.z, A.w);
      unsigned u2 = cvtpk(Bv.x, Bv.y), u3 = cvtpk(Bv.z, Bv.w);
      if (gg == 2) {
        unsigned l0 = cvtpk(A.x - lo2f(u0), A.y - hi2f(u0));
        unsigned l1 = cvtpk(A.z - lo2f(u1), A.w - hi2f(u1));
        unsigned l2 = cvtpk(Bv.x - lo2f(u2), Bv.y - hi2f(u2));
        unsigned l3 = cvtpk(Bv.z - lo2f(u3), Bv.w - hi2f(u3));
        bx = pack4(l0, l1, l2, l3);
      } else {
        bx = pack4(u0, u1, u2, u3);
      }
    }

    floatx4 acc = zf4;
    for (int blkI = 0; blkI < BPW; ++blkI) {
      FragBlk f2 = f1;
      if (blkI + 2 < BPW) f2 = ldblk(pbw + (blkI + 2) * 2048);
      floatx4 h0 = mfma16(f0.a0, bx, zf4);
      floatx4 h1 = mfma16(f0.a1, bx, zf4);
      float v0 = fmaxf(h0[0], 0.f), v1 = fmaxf(h0[1], 0.f);
      float v2 = fmaxf(h0[2], 0.f), v3 = fmaxf(h0[3], 0.f);
      float v4 = fmaxf(h1[0], 0.f), v5 = fmaxf(h1[1], 0.f);
      float v6 = fmaxf(h1[2], 0.f), v7 = fmaxf(h1[3], 0.f);
      unsigned u0 = cvtpk(v0, v1), u1 = cvtpk(v2, v3);
      unsigned u2 = cvtpk(v4, v5), u3 = cvtpk(v6, v7);
      unsigned l0 = cvtpk(v0 - lo2f(u0), v1 - hi2f(u0));
      unsigned l1 = cvtpk(v2 - lo2f(u1), v3 - hi2f(u1));
      unsigned l2 = cvtpk(v4 - lo2f(u2), v5 - hi2f(u2));
      unsigned l3 = cvtpk(v6 - lo2f(u3), v7 - hi2f(u3));
      short8 ah = pack4(u0, u1, u2, u3);
      short8 al = pack4(l0, l1, l2, l3);
      acc = mfma16(f0.w2h, ah, acc);
      acc = mfma16(f0.w2h, al, acc);
      acc = mfma16(f0.w2l, ah, acc);
      f0 = f1; f1 = f2;
    }

    *(floatx4*)&red[(wave << 10) + (lane << 2)] = acc;
    __syncthreads();
    if (tid == 0) {
      float o[8];
#pragma unroll
      for (int d = 0; d < 8; ++d) {
        float s = X[t][d] + b2[d];
        int base = ((d >> 2) << 6) + (d & 3);   // lane (gg=d>>2, rr=0) reg d&3
#pragma unroll
        for (int w = 0; w < NW; ++w) s += red[(w << 10) + base];
        o[d] = s;
      }
      float m = 0.f;
#pragma unroll
      for (int k = 0; k < 8; ++k) m += o[k];
      m *= 0.125f;
      float var = 0.f;
#pragma unroll
      for (int k = 0; k < 8; ++k) { float dm = o[k] - m; var += dm * dm; }
      float rs = rsqrtf(var * 0.125f + 1e-5f);
#pragma unroll
      for (int k = 0; k < 8; ++k) X[t][k] = (o[k] - m) * rs * g[k] + bb[k];
    }
    __syncthreads();
  };

  // ---------------- the 60-step scan ----------------
  for (int t = 0; t < T; ++t) {
    const int R = t + 1;
    const int Mt = (R + 15) >> 4;

    for (int o = tid; o < 512; o += NT) {
      int r = o >> 3, d = o & 7;
      X[r][d] = (r < R) ? buf[r][d] : 0.f;
    }
    __syncthreads();

    // encoder: 6 layers, keys <= t. FFN blocks 0/1 preloaded under oproj_ln.
    for (int li = 0; li < 6; ++li) {
      const short* pbw = ws + li * LSTR + wave * BPW * 2048;
      mha_qa(li, X, false, R);
      FragBlk f0 = ldblk(pbw);
      FragBlk f1 = ldblk(pbw + 2048);
      oproj_ln(&wAll[li * 288], lnp[li * 4 + 0], lnp[li * 4 + 1], R);
      __syncthreads();
      ffn(f0, f1, pbw, b2all[li], lnp[li * 4 + 2], lnp[li * 4 + 3], R, Mt);
    }
    ln_rows(X, X, lnp[24], lnp[25], R);
    __syncthreads();
    for (int o = tid; o < 512; o += NT) {
      int r = o >> 3, d = o & 7;
      if (r < R) Mem[r][d] = X[r][d];
      X[r][d] = (r < R) ? buf[r][d] : 0.f;
    }
    __syncthreads();

    // decoder layer 1: full (its rows are layer-2 self-attn keys)
    mha(6, X, true, R, lnp[26], lnp[27]);
    {
      const short* pbw = ws + 6 * LSTR + wave * BPW * 2048;
      mha_qa(7, Mem, false, R);
      FragBlk f0 = ldblk(pbw);
      FragBlk f1 = ldblk(pbw + 2048);
      oproj_ln(&wAll[7 * 288], lnp[28], lnp[29], R);
      __syncthreads();
      ffn(f0, f1, pbw, b2all[6], lnp[30], lnp[31], R, Mt);
    }

    // decoder layer 2: ONLY row t is ever consumed downstream
    mha_row(8, X, R, t, lnp[32], lnp[33]);
    {
      const short* pbw = ws + 7 * LSTR + wave * BPW * 2048;
      mha_row_qa(9, Mem, R, t);
      FragBlk f0 = ldblk(pbw);
      FragBlk f1 = ldblk(pbw + 2048);
      oproj_row(&wAll[9 * 288], lnp[34], lnp[35], t);
      __syncthreads();
      ffn_row(f0, f1, pbw, b2all[7], lnp[36], lnp[37], t);
    }

    // final LN (row t) + st = y[t] @ fc_W^T + fc_b -> out; embed to buf[t+1]
    if (tid == 0) {
      float o[8];
#pragma unroll
      for (int k = 0; k < 8; ++k) o[k] = X[t][k];
      float m = 0.f;
#pragma unroll
      for (int k = 0; k < 8; ++k) m += o[k];
      m *= 0.125f;
      float v = 0.f;
#pragma unroll
      for (int k = 0; k < 8; ++k) { float dm = o[k] - m; v += dm * dm; }
      float rs = rsqrtf(v * 0.125f + 1e-5f);
#pragma unroll
      for (int k = 0; k < 8; ++k) X[t][k] = (o[k] - m) * rs * lnp[38][k] + lnp[39][k];
    }
    __syncthreads();
    if (tid < SD) {
      float s = fcbv[tid];
#pragma unroll
      for (int k = 0; k < 8; ++k) s += X[t][k] * fcw[tid][k];
      stv[tid] = s;
      P.out[(b * T + t) * SD + tid] = s;
    }
    __syncthreads();
    if (t + 1 < T && tid < D) {
      float s = embbv[tid];
#pragma unroll
      for (int k = 0; k < SD; ++k) s += stv[k] * embw[tid][k];
      buf[t + 1][tid] = s;
    }
    __syncthreads();
  }
}

extern "C" void kernel_launch(void* const* d_in, const int* in_sizes, int n_in,
                              void* d_out, int out_size, void* d_ws, size_t ws_size,
                              hipStream_t stream) {
  (void)in_sizes; (void)n_in; (void)ws_size; (void)out_size;
  Params P;
  for (int i = 0; i < 39; ++i) P.in[i] = (const float*)d_in[i];
  P.out = (float*)d_out;
  short* ws = (short*)d_ws;   // 8 layers * 256KB = 2MB of packed fragments
  repack_kernel<<<dim3(8 * NBLK), dim3(64), 0, stream>>>(P, ws);
  tdec_kernel<<<dim3(128), dim3(NT), 0, stream>>>(P, ws);
}

// Round 14
// 3383.296 us; speedup vs baseline: 1.1162x; 1.0616x over previous
//
#include <hip/hip_runtime.h>

// TransformerDecoder scan: B=128 independent sequences, one workgroup each,
// 8 waves/WG (NT=512; r12 proved 16 waves issue-neutral + L2-thrash).
// Round-14: r10 base (3473us best; r13 preload reverted — +64 VGPR, no win)
// + ONE change: attention j-loop manually unrolled x4 with float2 K/V loads
// (rolled loop paid ~120cyc LDS latency per iteration — the only rolled
// LDS-load loop in the kernel). Bit-identical FP order per thread.
// FROZEN: FFN 3-term hi/lo (r9: h-lo load-bearing, scan amplifies ~x800),
// repack, row-t decoder specialization, single-thread-per-row epilogues.

typedef __attribute__((ext_vector_type(8))) short short8;
typedef __attribute__((ext_vector_type(4))) float floatx4;
typedef __attribute__((ext_vector_type(4))) unsigned uint4v;

#define DEV static __device__ __forceinline__

namespace {
constexpr int D   = 8;
constexpr int T   = 60;
constexpr int DFF = 2048;
constexpr int SD  = 17;
constexpr int NT  = 512;             // 8 waves
constexpr int NW  = NT / 64;
constexpr int NBLK = DFF / 32;       // 64 blocks of 32 hidden cols
constexpr int BPW  = NBLK / NW;      // 8 blocks per wave
constexpr int LSTR = NBLK * 2048;    // shorts per layer in ws (256KB)
}

struct Params { const float* in[39]; float* out; };

// fp32 -> bf16 (round-half-up) — repack-time only
DEV unsigned short f2bf(float f) {
  unsigned u = __builtin_bit_cast(unsigned, f);
  return (unsigned short)((u + 0x8000u) >> 16);
}
DEV float bf2f(unsigned short h) {
  unsigned u = ((unsigned)h) << 16;
  return __builtin_bit_cast(float, u);
}
DEV floatx4 mfma16(short8 a, short8 b, floatx4 c) {
  return __builtin_amdgcn_mfma_f32_16x16x32_bf16(a, b, c, 0, 0, 0);
}
// packed fp32->bf16 (RTNE), 2 values -> 1 dword. No builtin on gfx950.
DEV unsigned cvtpk(float lo, float hi) {
  unsigned r;
  asm("v_cvt_pk_bf16_f32 %0, %1, %2" : "=v"(r) : "v"(lo), "v"(hi));
  return r;
}
DEV float lo2f(unsigned u) { return __builtin_bit_cast(float, u << 16); }
DEV float hi2f(unsigned u) { return __builtin_bit_cast(float, u & 0xffff0000u); }
DEV short8 pack4(unsigned a, unsigned b, unsigned c, unsigned d) {
  uint4v u = {a, b, c, d};
  return __builtin_bit_cast(short8, u);
}

// ---------------------------------------------------------------------------
// Repack kernel: per (layer L, 32-hidden block blk) write 2048 shorts:
//   [0:512) W1 A-frag tile 2*blk | [512:1024) tile 2*blk+1
//   [1024:1536) W2 A-frag hi     | [1536:2048) W2 A-frag lo
// W1 A-frag lane (gg,rr): gg0=hi(W1[j0+rr][0..7]) gg1=lo gg2=hi(dup)
//                         gg3={b1_hi,b1_lo,0..} (bias folded, B supplies 1.0)
// W2 A-frag lane (gg,rr), rr<8: W2[rr][jsel(gg,i)],
//   jsel(gg,i)= j0 + (i<4 ? gg*4+i : 16+gg*4+(i-4))  — matches the FFN1
//   output fragment order so FFN2's B-operand is lane-local.
// ---------------------------------------------------------------------------
__global__ __launch_bounds__(64) void repack_kernel(Params P, short* ws) {
  const int wg = blockIdx.x;              // 8 layers * 64 blocks
  const int L = wg >> 6, blk = wg & 63;
  const int l = (int)threadIdx.x, gg = l >> 4, rr = l & 15;
  const float *W1p, *b1p, *W2p;
  if (L < 6) { W1p = P.in[7] + L * 16384;  b1p = P.in[8] + L * 2048;  W2p = P.in[9] + L * 16384; }
  else { int m = L - 6; W1p = P.in[25] + m * 16384; b1p = P.in[26] + m * 2048; W2p = P.in[27] + m * 16384; }
  short* out = ws + (L * 64 + blk) * 2048;
  const int j0 = blk * 32;
  short8 z = {0,0,0,0,0,0,0,0};
  for (int tt = 0; tt < 2; ++tt) {
    int j = j0 + tt * 16 + rr;
    short8 r = z;
    if (gg == 3) {
      unsigned short h = f2bf(b1p[j]);
      r[0] = (short)h; r[1] = (short)f2bf(b1p[j] - bf2f(h));
    } else {
      const float* p = W1p + j * 8;
#pragma unroll
      for (int i = 0; i < 8; ++i) {
        float v = p[i];
        unsigned short h = f2bf(v);
        r[i] = (short)((gg == 1) ? f2bf(v - bf2f(h)) : h);
      }
    }
    *(short8*)(out + tt * 512 + l * 8) = r;
  }
  short8 wh = z, wl = z;
  if (rr < 8) {
#pragma unroll
    for (int i = 0; i < 8; ++i) {
      int j = j0 + (i < 4 ? gg * 4 + i : 16 + gg * 4 + (i - 4));
      float v = W2p[rr * 2048 + j];
      unsigned short h = f2bf(v);
      wh[i] = (short)h;
      wl[i] = (short)f2bf(v - bf2f(h));
    }
  }
  *(short8*)(out + 1024 + l * 8) = wh;
  *(short8*)(out + 1536 + l * 8) = wl;
}

// ---------------------------------------------------------------------------
__global__ __launch_bounds__(NT, 2) void tdec_kernel(Params P, const short* ws) {
  const int b    = blockIdx.x;
  const int tid  = (int)threadIdx.x;
  const int lane = tid & 63;
  const int wave = tid >> 6;
  const int gg   = lane >> 4;   // k-group within MFMA
  const int rr   = lane & 15;   // row/col within 16-tile

  __shared__ float buf[T][D];
  __shared__ __align__(16) float X[64][D];   // zero-padded rows >= R
  __shared__ float Mem[64][D];
  __shared__ __align__(16) float Qs[64][D];
  __shared__ __align__(16) float Ks[64][D];
  __shared__ __align__(16) float Vs[64][D];
  __shared__ float ATT[64][D];
  __shared__ __align__(16) float red[NW * 1024];  // FFN cross-wave partials 32KB
  __shared__ float wAll[10 * 288];
  __shared__ float lnp[40][D];
  __shared__ float b2all[8][D];
  __shared__ float fcw[SD][D];
  __shared__ float fcbv[SD];
  __shared__ float embw[D][SD];
  __shared__ float embbv[D];
  __shared__ float stv[SD];

  // ---------------- one-time staging of all small weights ----------------
  for (int o = tid; o < 2880; o += NT) {
    int a = o / 288, off = o - a * 288;
    const float *Wq, *Bq, *Wo, *Bo; int li;
    if (a < 6)              { li = a;            Wq=P.in[3];  Bq=P.in[4];  Wo=P.in[5];  Bo=P.in[6];  }
    else if (((a - 6) & 1) == 0) { li = (a-6)>>1; Wq=P.in[17]; Bq=P.in[18]; Wo=P.in[19]; Bo=P.in[20]; }
    else                    { li = (a-6)>>1;     Wq=P.in[21]; Bq=P.in[22]; Wo=P.in[23]; Bo=P.in[24]; }
    float v;
    if (off < 192)      v = Wq[li*192 + off];
    else if (off < 216) v = Bq[li*24  + off - 192];
    else if (off < 280) v = Wo[li*64  + off - 216];
    else                v = Bo[li*8   + off - 280];
    wAll[o] = v;
  }
  for (int o = tid; o < 320; o += NT) {
    int row = o >> 3, k = o & 7;
    const float* src;
    if (row < 24) { int li = row >> 2, w = row & 3;
      src = (w==0 ? P.in[11] : w==1 ? P.in[12] : w==2 ? P.in[13] : P.in[14]) + li*8;
    } else if (row < 26) src = (row == 24 ? P.in[15] : P.in[16]);
    else if (row < 38) { int q = row - 26, li = q / 6, w = q - li*6;
      src = (w==0?P.in[29]:w==1?P.in[30]:w==2?P.in[31]:w==3?P.in[32]:w==4?P.in[33]:P.in[34]) + li*8;
    } else src = (row == 38 ? P.in[35] : P.in[36]);
    lnp[row][k] = src[k];
  }
  if (tid < 64) { int row = tid >> 3, k = tid & 7;
    b2all[row][k] = (row < 6) ? P.in[10][row*8 + k] : P.in[28][(row-6)*8 + k]; }
  if (tid < 136) fcw[tid >> 3][tid & 7] = P.in[37][tid];
  if (tid < SD)  fcbv[tid] = P.in[38][tid];
  if (tid < 136) embw[tid / 17][tid % 17] = P.in[1][tid];
  if (tid < D)   embbv[tid] = P.in[2][tid];
  if (tid < D)   buf[0][tid] = P.in[0][b*D + tid];
  __syncthreads();

  const short8 zero8 = {0,0,0,0,0,0,0,0};
  const floatx4 zf4  = {0.f,0.f,0.f,0.f};

  // ---------------- helpers ----------------
  auto proj8 = [&](float (*dst)[D], const float (*src)[D], const float* w,
                   const float* bias, int R) {
    for (int o = tid; o < (R << 3); o += NT) {
      int r = o >> 3, d = o & 7;
      const float* wr = w + d * 8;
      const float* xr = src[r];
      float s = bias[d];
#pragma unroll
      for (int k = 0; k < 8; ++k) s += xr[k] * wr[k];
      dst[r][d] = s;
    }
  };

  // attention inner sum for one (p, h2) over j = e, e+stride, ..., <= lim.
  // Manually unrolled x4 with float2 K/V loads: batches 8 LDS loads in
  // flight per iteration (rolled form paid ~120cyc latency per j).
  // Accumulation order identical to the rolled loop -> bit-identical.
  auto attn_core = [&](float q0, float q1, int e, int stride, int lim,
                       float& l, float& a0, float& a1) {
    int j = e;
    int s3 = 3 * stride;
    for (; j + s3 <= lim; j += 4 * stride) {
      float2 k0 = *(const float2*)&Ks[j][0] ;  // placeholder, replaced below
      (void)k0;
      break;
    }
    // (the lambda above is specialized per h2 at the call site)
  };
  (void)attn_core;

  // fixed-shift single-pass softmax (LN-bounded scores; exp(s-10) safe).
  // 4 threads per (p,h) when R<=32, else 2; shfl_xor combine.
  auto attn = [&](int R, bool causal) {
    if (R <= 32) {
      int p = tid >> 4, h2 = ((tid >> 2) & 3) << 1, e = tid & 3;
      if (p < R) {
        float q0 = Qs[p][h2]     * 0.70710678118654752f;
        float q1 = Qs[p][h2 + 1] * 0.70710678118654752f;
        int lim = causal ? p : (R - 1);
        float l = 0.f, a0 = 0.f, a1 = 0.f;
        int j = e;
        for (; j + 12 <= lim; j += 16) {
          float2 k0 = *(const float2*)&Ks[j     ][h2];
          float2 k1 = *(const float2*)&Ks[j +  4][h2];
          float2 k2 = *(const float2*)&Ks[j +  8][h2];
          float2 k3 = *(const float2*)&Ks[j + 12][h2];
          float2 v0 = *(const float2*)&Vs[j     ][h2];
          float2 v1 = *(const float2*)&Vs[j +  4][h2];
          float2 v2 = *(const float2*)&Vs[j +  8][h2];
          float2 v3 = *(const float2*)&Vs[j + 12][h2];
          float e0 = __expf(q0 * k0.x + q1 * k0.y - 10.f);
          float e1 = __expf(q0 * k1.x + q1 * k1.y - 10.f);
          float e2 = __expf(q0 * k2.x + q1 * k2.y - 10.f);
          float e3 = __expf(q0 * k3.x + q1 * k3.y - 10.f);
          l += e0; a0 += e0 * v0.x; a1 += e0 * v0.y;
          l += e1; a0 += e1 * v1.x; a1 += e1 * v1.y;
          l += e2; a0 += e2 * v2.x; a1 += e2 * v2.y;
          l += e3; a0 += e3 * v3.x; a1 += e3 * v3.y;
        }
        for (; j <= lim; j += 4) {
          float2 kk = *(const float2*)&Ks[j][h2];
          float2 vv = *(const float2*)&Vs[j][h2];
          float ev = __expf(q0 * kk.x + q1 * kk.y - 10.f);
          l += ev; a0 += ev * vv.x; a1 += ev * vv.y;
        }
        l  += __shfl_xor(l, 1);  l  += __shfl_xor(l, 2);
        a0 += __shfl_xor(a0, 1); a0 += __shfl_xor(a0, 2);
        a1 += __shfl_xor(a1, 1); a1 += __shfl_xor(a1, 2);
        if (e == 0) {
          float rl = 1.f / l;
          ATT[p][h2] = a0 * rl; ATT[p][h2 + 1] = a1 * rl;
        }
      }
    } else {
      int p = tid >> 3, h2 = ((tid >> 1) & 3) << 1, e = tid & 1;
      if (p < R) {
        float q0 = Qs[p][h2]     * 0.70710678118654752f;
        float q1 = Qs[p][h2 + 1] * 0.70710678118654752f;
        int lim = causal ? p : (R - 1);
        float l = 0.f, a0 = 0.f, a1 = 0.f;
        int j = e;
        for (; j + 6 <= lim; j += 8) {
          float2 k0 = *(const float2*)&Ks[j    ][h2];
          float2 k1 = *(const float2*)&Ks[j + 2][h2];
          float2 k2 = *(const float2*)&Ks[j + 4][h2];
          float2 k3 = *(const float2*)&Ks[j + 6][h2];
          float2 v0 = *(const float2*)&Vs[j    ][h2];
          float2 v1 = *(const float2*)&Vs[j + 2][h2];
          float2 v2 = *(const float2*)&Vs[j + 4][h2];
          float2 v3 = *(const float2*)&Vs[j + 6][h2];
          float e0 = __expf(q0 * k0.x + q1 * k0.y - 10.f);
          float e1 = __expf(q0 * k1.x + q1 * k1.y - 10.f);
          float e2 = __expf(q0 * k2.x + q1 * k2.y - 10.f);
          float e3 = __expf(q0 * k3.x + q1 * k3.y - 10.f);
          l += e0; a0 += e0 * v0.x; a1 += e0 * v0.y;
          l += e1; a0 += e1 * v1.x; a1 += e1 * v1.y;
          l += e2; a0 += e2 * v2.x; a1 += e2 * v2.y;
          l += e3; a0 += e3 * v3.x; a1 += e3 * v3.y;
        }
        for (; j <= lim; j += 2) {
          float2 kk = *(const float2*)&Ks[j][h2];
          float2 vv = *(const float2*)&Vs[j][h2];
          float ev = __expf(q0 * kk.x + q1 * kk.y - 10.f);
          l += ev; a0 += ev * vv.x; a1 += ev * vv.y;
        }
        l  += __shfl_xor(l, 1);
        a0 += __shfl_xor(a0, 1);
        a1 += __shfl_xor(a1, 1);
        if (e == 0) {
          float rl = 1.f / l;
          ATT[p][h2] = a0 * rl; ATT[p][h2 + 1] = a1 * rl;
        }
      }
    }
  };

  auto oproj_ln = [&](const float* wo, const float* bo, const float* g,
                      const float* bb, int R) {
    if (tid < R) {
      float o[8];
#pragma unroll
      for (int d = 0; d < 8; ++d) {
        float s = bo[d] + X[tid][d];
#pragma unroll
        for (int k = 0; k < 8; ++k) s += ATT[tid][k] * wo[d * 8 + k];
        o[d] = s;
      }
      float m = 0.f;
#pragma unroll
      for (int k = 0; k < 8; ++k) m += o[k];
      m *= 0.125f;
      float v = 0.f;
#pragma unroll
      for (int k = 0; k < 8; ++k) { float dm = o[k] - m; v += dm * dm; }
      float rs = rsqrtf(v * 0.125f + 1e-5f);
#pragma unroll
      for (int k = 0; k < 8; ++k) X[tid][k] = (o[k] - m) * rs * g[k] + bb[k];
    }
  };

  auto ln_rows = [&](float (*dst)[D], const float (*src)[D], const float* g,
                     const float* bb, int R) {
    if (tid < R) {
      float o[8];
#pragma unroll
      for (int k = 0; k < 8; ++k) o[k] = src[tid][k];
      float m = 0.f;
#pragma unroll
      for (int k = 0; k < 8; ++k) m += o[k];
      m *= 0.125f;
      float v = 0.f;
#pragma unroll
      for (int k = 0; k < 8; ++k) { float dm = o[k] - m; v += dm * dm; }
      float rs = rsqrtf(v * 0.125f + 1e-5f);
#pragma unroll
      for (int k = 0; k < 8; ++k) dst[tid][k] = (o[k] - m) * rs * g[k] + bb[k];
    }
  };

  auto mha = [&](int a, float (*kvsrc)[D], bool causal, int R,
                 const float* g, const float* bb) {
    const float* wq = &wAll[a * 288];
    proj8(Qs, X,     wq +   0, wq + 192, R);
    proj8(Ks, kvsrc, wq +  64, wq + 200, R);
    proj8(Vs, kvsrc, wq + 128, wq + 208, R);
    __syncthreads();
    attn(R, causal);
    __syncthreads();
    oproj_ln(wq + 216, wq + 280, g, bb, R);
    __syncthreads();
  };

  // MHA computing ONLY row t of the output (K/V proj still full R rows).
  auto mha_row = [&](int a, float (*kvsrc)[D], int R, int t,
                     const float* g, const float* bb) {
    const float* wq = &wAll[a * 288];
    proj8(Ks, kvsrc, wq +  64, wq + 200, R);
    proj8(Vs, kvsrc, wq + 128, wq + 208, R);
    if (tid < 8) {                      // Q projection, row t only
      int d = tid;
      const float* wr = wq + d * 8;
      float s = wq[192 + d];
#pragma unroll
      for (int k = 0; k < 8; ++k) s += X[t][k] * wr[k];
      Qs[t][d] = s;
    }
    __syncthreads();
    if (tid < 32) {                     // attention row t: 8-way j-split
      int h2 = (tid >> 3) << 1, e = tid & 7;
      float q0 = Qs[t][h2]     * 0.70710678118654752f;
      float q1 = Qs[t][h2 + 1] * 0.70710678118654752f;
      float l = 0.f, a0 = 0.f, a1 = 0.f;
      int j = e;
      for (; j + 24 < R; j += 32) {
        float2 k0 = *(const float2*)&Ks[j     ][h2];
        float2 k1 = *(const float2*)&Ks[j +  8][h2];
        float2 k2 = *(const float2*)&Ks[j + 16][h2];
        float2 k3 = *(const float2*)&Ks[j + 24][h2];
        float2 v0 = *(const float2*)&Vs[j     ][h2];
        float2 v1 = *(const float2*)&Vs[j +  8][h2];
        float2 v2 = *(const float2*)&Vs[j + 16][h2];
        float2 v3 = *(const float2*)&Vs[j + 24][h2];
        float e0 = __expf(q0 * k0.x + q1 * k0.y - 10.f);
        float e1 = __expf(q0 * k1.x + q1 * k1.y - 10.f);
        float e2 = __expf(q0 * k2.x + q1 * k2.y - 10.f);
        float e3 = __expf(q0 * k3.x + q1 * k3.y - 10.f);
        l += e0; a0 += e0 * v0.x; a1 += e0 * v0.y;
        l += e1; a0 += e1 * v1.x; a1 += e1 * v1.y;
        l += e2; a0 += e2 * v2.x; a1 += e2 * v2.y;
        l += e3; a0 += e3 * v3.x; a1 += e3 * v3.y;
      }
      for (; j < R; j += 8) {
        float2 kk = *(const float2*)&Ks[j][h2];
        float2 vv = *(const float2*)&Vs[j][h2];
        float ev = __expf(q0 * kk.x + q1 * kk.y - 10.f);
        l += ev; a0 += ev * vv.x; a1 += ev * vv.y;
      }
      l  += __shfl_xor(l, 1);  l  += __shfl_xor(l, 2);  l  += __shfl_xor(l, 4);
      a0 += __shfl_xor(a0, 1); a0 += __shfl_xor(a0, 2); a0 += __shfl_xor(a0, 4);
      a1 += __shfl_xor(a1, 1); a1 += __shfl_xor(a1, 2); a1 += __shfl_xor(a1, 4);
      if (e == 0) {
        float rl = 1.f / l;
        ATT[t][h2] = a0 * rl; ATT[t][h2 + 1] = a1 * rl;
      }
    }
    __syncthreads();
    if (tid == 0) {                     // oproj + residual + LN, row t
      float o[8];
#pragma unroll
      for (int d = 0; d < 8; ++d) {
        float s = wq[280 + d] + X[t][d];
#pragma unroll
        for (int k = 0; k < 8; ++k) s += ATT[t][k] * wq[216 + d * 8 + k];
        o[d] = s;
      }
      float m = 0.f;
#pragma unroll
      for (int k = 0; k < 8; ++k) m += o[k];
      m *= 0.125f;
      float v = 0.f;
#pragma unroll
      for (int k = 0; k < 8; ++k) { float dm = o[k] - m; v += dm * dm; }
      float rs = rsqrtf(v * 0.125f + 1e-5f);
#pragma unroll
      for (int k = 0; k < 8; ++k) X[t][k] = (o[k] - m) * rs * g[k] + bb[k];
    }
    __syncthreads();
  };

  // FFN, swapped-operand form (r5 3-term arithmetic — FROZEN).
  auto ffn = [&](const short* wsL, const float* b2, const float* g,
                 const float* bb, int R, int Mt) {
    // issue block-0 fragment loads first; bx-setup VALU hides the latency
    const short* pb = wsL + (wave * BPW) * 2048;
    short8 a0  = *(const short8*)(pb + lane * 8);
    short8 a1  = *(const short8*)(pb + 512 + lane * 8);
    short8 w2h = *(const short8*)(pb + 1024 + lane * 8);
    short8 w2l = *(const short8*)(pb + 1536 + lane * 8);

    // B-frags (X^T) per r-tile; lane variant: gg0/1=x_hi, gg2=x_lo, gg3=ones
    short8 bx[4];
#pragma unroll
    for (int mt = 0; mt < 4; ++mt) {
      short8 v = zero8;
      if (mt < Mt) {
        if (gg == 3) { v[0] = (short)0x3F80; v[1] = (short)0x3F80; }
        else {
          int r = mt * 16 + rr;
          float4 A = *(const float4*)&X[r][0];
          float4 Bv = *(const float4*)&X[r][4];
          unsigned u0 = cvtpk(A.x, A.y), u1 = cvtpk(A.z, A.w);
          unsigned u2 = cvtpk(Bv.x, Bv.y), u3 = cvtpk(Bv.z, Bv.w);
          if (gg == 2) {
            unsigned l0 = cvtpk(A.x - lo2f(u0), A.y - hi2f(u0));
            unsigned l1 = cvtpk(A.z - lo2f(u1), A.w - hi2f(u1));
            unsigned l2 = cvtpk(Bv.x - lo2f(u2), Bv.y - hi2f(u2));
            unsigned l3 = cvtpk(Bv.z - lo2f(u3), Bv.w - hi2f(u3));
            v = pack4(l0, l1, l2, l3);
          } else {
            v = pack4(u0, u1, u2, u3);
          }
        }
      }
      bx[mt] = v;
    }

    floatx4 acc[4] = {zf4, zf4, zf4, zf4};
    for (int blkI = 0; blkI < BPW; ++blkI) {
      short8 na0 = zero8, na1 = zero8, nw2h = zero8, nw2l = zero8;
      if (blkI + 1 < BPW) {            // prefetch next block's fragments
        const short* pn = pb + (blkI + 1) * 2048;
        na0  = *(const short8*)(pn + lane * 8);
        na1  = *(const short8*)(pn + 512 + lane * 8);
        nw2h = *(const short8*)(pn + 1024 + lane * 8);
        nw2l = *(const short8*)(pn + 1536 + lane * 8);
      }
#pragma unroll
      for (int mt = 0; mt < 4; ++mt) {
        if (mt < Mt) {
          floatx4 h0 = mfma16(a0, bx[mt], zf4);   // rows j0..j0+15, cols=pos
          floatx4 h1 = mfma16(a1, bx[mt], zf4);   // rows j0+16..j0+31
          float v0 = fmaxf(h0[0], 0.f), v1 = fmaxf(h0[1], 0.f);
          float v2 = fmaxf(h0[2], 0.f), v3 = fmaxf(h0[3], 0.f);
          float v4 = fmaxf(h1[0], 0.f), v5 = fmaxf(h1[1], 0.f);
          float v6 = fmaxf(h1[2], 0.f), v7 = fmaxf(h1[3], 0.f);
          unsigned u0 = cvtpk(v0, v1), u1 = cvtpk(v2, v3);
          unsigned u2 = cvtpk(v4, v5), u3 = cvtpk(v6, v7);
          unsigned l0 = cvtpk(v0 - lo2f(u0), v1 - hi2f(u0));
          unsigned l1 = cvtpk(v2 - lo2f(u1), v3 - hi2f(u1));
          unsigned l2 = cvtpk(v4 - lo2f(u2), v5 - hi2f(u2));
          unsigned l3 = cvtpk(v6 - lo2f(u3), v7 - hi2f(u3));
          short8 ah = pack4(u0, u1, u2, u3);
          short8 al = pack4(l0, l1, l2, l3);
          // A-operand = W2 (rows = d), B-operand = h (cols = pos):
          // D[row=d][col=pos] matches the reduce below.
          acc[mt] = mfma16(w2h, ah, acc[mt]);
          acc[mt] = mfma16(w2h, al, acc[mt]);
          acc[mt] = mfma16(w2l, ah, acc[mt]);
        }
      }
      a0 = na0; a1 = na1; w2h = nw2h; w2l = nw2l;
    }

    // cross-wave reduce + residual + bias + LN, fused per row
#pragma unroll
    for (int mt = 0; mt < 4; ++mt)
      if (mt < Mt)
        *(floatx4*)&red[(((wave << 2) + mt) << 8) + (lane << 2)] = acc[mt];
    __syncthreads();
    if (tid < R) {
      int r = tid, mt = r >> 4, rl = r & 15;
      float o[8];
#pragma unroll
      for (int d = 0; d < 8; ++d) {
        float s = X[r][d] + b2[d];
        // acc layout: lane (gg=d>>2, rr=rl) reg (d&3) holds out^T[d][mt*16+rl]
        int base = (mt << 8) + ((((d >> 2) << 4) + rl) << 2) + (d & 3);
#pragma unroll
        for (int w = 0; w < NW; ++w) s += red[(w << 10) + base];
        o[d] = s;
      }
      float m = 0.f;
#pragma unroll
      for (int k = 0; k < 8; ++k) m += o[k];
      m *= 0.125f;
      float var = 0.f;
#pragma unroll
      for (int k = 0; k < 8; ++k) { float dm = o[k] - m; var += dm * dm; }
      float rs = rsqrtf(var * 0.125f + 1e-5f);
#pragma unroll
      for (int k = 0; k < 8; ++k) X[r][k] = (o[k] - m) * rs * g[k] + bb[k];
    }
    __syncthreads();
  };

  // FFN computing ONLY row t (column 0 of tile 0; k-sum column-independent
  // so the row-t result is bit-identical to full ffn).
  auto ffn_row = [&](const short* wsL, const float* b2, const float* g,
                     const float* bb, int t) {
    const short* pb = wsL + (wave * BPW) * 2048;
    short8 a0  = *(const short8*)(pb + lane * 8);
    short8 a1  = *(const short8*)(pb + 512 + lane * 8);
    short8 w2h = *(const short8*)(pb + 1024 + lane * 8);
    short8 w2l = *(const short8*)(pb + 1536 + lane * 8);

    short8 bx = zero8;
    if (gg == 3) { bx[0] = (short)0x3F80; bx[1] = (short)0x3F80; }
    else if (rr == 0) {
      float4 A = *(const float4*)&X[t][0];
      float4 Bv = *(const float4*)&X[t][4];
      unsigned u0 = cvtpk(A.x, A.y), u1 = cvtpk(A.z, A.w);
      unsigned u2 = cvtpk(Bv.x, Bv.y), u3 = cvtpk(Bv.z, Bv.w);
      if (gg == 2) {
        unsigned l0 = cvtpk(A.x - lo2f(u0), A.y - hi2f(u0));
        unsigned l1 = cvtpk(A.z - lo2f(u1), A.w - hi2f(u1));
        unsigned l2 = cvtpk(Bv.x - lo2f(u2), Bv.y - hi2f(u2));
        unsigned l3 = cvtpk(Bv.z - lo2f(u3), Bv.w - hi2f(u3));
        bx = pack4(l0, l1, l2, l3);
      } else {
        bx = pack4(u0, u1, u2, u3);
      }
    }

    floatx4 acc = zf4;
    for (int blkI = 0; blkI < BPW; ++blkI) {
      short8 na0 = zero8, na1 = zero8, nw2h = zero8, nw2l = zero8;
      if (blkI + 1 < BPW) {
        const short* pn = pb + (blkI + 1) * 2048;
        na0  = *(const short8*)(pn + lane * 8);
        na1  = *(const short8*)(pn + 512 + lane * 8);
        nw2h = *(const short8*)(pn + 1024 + lane * 8);
        nw2l = *(const short8*)(pn + 1536 + lane * 8);
      }
      floatx4 h0 = mfma16(a0, bx, zf4);
      floatx4 h1 = mfma16(a1, bx, zf4);
      float v0 = fmaxf(h0[0], 0.f), v1 = fmaxf(h0[1], 0.f);
      float v2 = fmaxf(h0[2], 0.f), v3 = fmaxf(h0[3], 0.f);
      float v4 = fmaxf(h1[0], 0.f), v5 = fmaxf(h1[1], 0.f);
      float v6 = fmaxf(h1[2], 0.f), v7 = fmaxf(h1[3], 0.f);
      unsigned u0 = cvtpk(v0, v1), u1 = cvtpk(v2, v3);
      unsigned u2 = cvtpk(v4, v5), u3 = cvtpk(v6, v7);
      unsigned l0 = cvtpk(v0 - lo2f(u0), v1 - hi2f(u0));
      unsigned l1 = cvtpk(v2 - lo2f(u1), v3 - hi2f(u1));
      unsigned l2 = cvtpk(v4 - lo2f(u2), v5 - hi2f(u2));
      unsigned l3 = cvtpk(v6 - lo2f(u3), v7 - hi2f(u3));
      short8 ah = pack4(u0, u1, u2, u3);
      short8 al = pack4(l0, l1, l2, l3);
      acc = mfma16(w2h, ah, acc);
      acc = mfma16(w2h, al, acc);
      acc = mfma16(w2l, ah, acc);
      a0 = na0; a1 = na1; w2h = nw2h; w2l = nw2l;
    }

    *(floatx4*)&red[(wave << 10) + (lane << 2)] = acc;
    __syncthreads();
    if (tid == 0) {
      float o[8];
#pragma unroll
      for (int d = 0; d < 8; ++d) {
        float s = X[t][d] + b2[d];
        int base = ((d >> 2) << 6) + (d & 3);   // lane (gg=d>>2, rr=0) reg d&3
#pragma unroll
        for (int w = 0; w < NW; ++w) s += red[(w << 10) + base];
        o[d] = s;
      }
      float m = 0.f;
#pragma unroll
      for (int k = 0; k < 8; ++k) m += o[k];
      m *= 0.125f;
      float var = 0.f;
#pragma unroll
      for (int k = 0; k < 8; ++k) { float dm = o[k] - m; var += dm * dm; }
      float rs = rsqrtf(var * 0.125f + 1e-5f);
#pragma unroll
      for (int k = 0; k < 8; ++k) X[t][k] = (o[k] - m) * rs * g[k] + bb[k];
    }
    __syncthreads();
  };

  // ---------------- the 60-step scan ----------------
  for (int t = 0; t < T; ++t) {
    const int R = t + 1;
    const int Mt = (R + 15) >> 4;

    for (int o = tid; o < 512; o += NT) {
      int r = o >> 3, d = o & 7;
      X[r][d] = (r < R) ? buf[r][d] : 0.f;
    }
    __syncthreads();

    // encoder: 6 layers, keys <= t
    for (int li = 0; li < 6; ++li) {
      mha(li, X, false, R, lnp[li * 4 + 0], lnp[li * 4 + 1]);
      ffn(ws + li * LSTR, b2all[li], lnp[li * 4 + 2], lnp[li * 4 + 3], R, Mt);
    }
    ln_rows(X, X, lnp[24], lnp[25], R);
    __syncthreads();
    for (int o = tid; o < 512; o += NT) {
      int r = o >> 3, d = o & 7;
      if (r < R) Mem[r][d] = X[r][d];
      X[r][d] = (r < R) ? buf[r][d] : 0.f;
    }
    __syncthreads();

    // decoder layer 1: full (its rows are layer-2 self-attn keys)
    mha(6, X,   true,  R, lnp[26], lnp[27]);
    mha(7, Mem, false, R, lnp[28], lnp[29]);
    ffn(ws + 6 * LSTR, b2all[6], lnp[30], lnp[31], R, Mt);

    // decoder layer 2: ONLY row t is ever consumed downstream
    mha_row(8, X,   R, t, lnp[32], lnp[33]);
    mha_row(9, Mem, R, t, lnp[34], lnp[35]);
    ffn_row(ws + 7 * LSTR, b2all[7], lnp[36], lnp[37], t);

    // final LN (row t) + st = y[t] @ fc_W^T + fc_b -> out; embed to buf[t+1]
    if (tid == 0) {
      float o[8];
#pragma unroll
      for (int k = 0; k < 8; ++k) o[k] = X[t][k];
      float m = 0.f;
#pragma unroll
      for (int k = 0; k < 8; ++k) m += o[k];
      m *= 0.125f;
      float v = 0.f;
#pragma unroll
      for (int k = 0; k < 8; ++k) { float dm = o[k] - m; v += dm * dm; }
      float rs = rsqrtf(v * 0.125f + 1e-5f);
#pragma unroll
      for (int k = 0; k < 8; ++k) X[t][k] = (o[k] - m) * rs * lnp[38][k] + lnp[39][k];
    }
    __syncthreads();
    if (tid < SD) {
      float s = fcbv[tid];
#pragma unroll
      for (int k = 0; k < 8; ++k) s += X[t][k] * fcw[tid][k];
      stv[tid] = s;
      P.out[(b * T + t) * SD + tid] = s;
    }
    __syncthreads();
    if (t + 1 < T && tid < D) {
      float s = embbv[tid];
#pragma unroll
      for (int k = 0; k < SD; ++k) s += stv[k] * embw[tid][k];
      buf[t + 1][tid] = s;
    }
    __syncthreads();
  }
}

extern "C" void kernel_launch(void* const* d_in, const int* in_sizes, int n_in,
                              void* d_out, int out_size, void* d_ws, size_t ws_size,
                              hipStream_t stream) {
  (void)in_sizes; (void)n_in; (void)ws_size; (void)out_size;
  Params P;
  for (int i = 0; i < 39; ++i) P.in[i] = (const float*)d_in[i];
  P.out = (float*)d_out;
  short* ws = (short*)d_ws;   // 8 layers * 256KB = 2MB of packed fragments
  repack_kernel<<<dim3(8 * NBLK), dim3(64), 0, stream>>>(P, ws);
  tdec_kernel<<<dim3(128), dim3(NT), 0, stream>>>(P, ws);
}

// Round 15
// 3333.571 us; speedup vs baseline: 1.1328x; 1.0149x over previous
//
#include <hip/hip_runtime.h>

// TransformerDecoder scan: B=128 independent sequences, one workgroup each,
// 8 waves/WG. Round-15: r14 base (3383us) + two bit-identical work deletions:
//  (a) decoder-L1 SELF-attention is causal over frozen buf rows -> its output
//      row p never changes after step p. Cache D1[p] + K6/V6 projections;
//      per step compute only row t (append-only incremental causal attn).
//  (b) encoder-L0 Q/K/V are projections of frozen buf rows -> cache Q0/K0/V0,
//      append row t; drop layer-0's proj8 phase entirely.
// FROZEN: FFN 3-term hi/lo (r9: h-lo load-bearing, scan amplifies ~x800),
// repack, row-t decoder-L2 specialization, unrolled attention (r14),
// single-thread-per-row epilogues, NT=512 (r12: 16 waves thrash L2).

typedef __attribute__((ext_vector_type(8))) short short8;
typedef __attribute__((ext_vector_type(4))) float floatx4;
typedef __attribute__((ext_vector_type(4))) unsigned uint4v;

#define DEV static __device__ __forceinline__

namespace {
constexpr int D   = 8;
constexpr int T   = 60;
constexpr int DFF = 2048;
constexpr int SD  = 17;
constexpr int NT  = 512;             // 8 waves
constexpr int NW  = NT / 64;
constexpr int NBLK = DFF / 32;       // 64 blocks of 32 hidden cols
constexpr int BPW  = NBLK / NW;      // 8 blocks per wave
constexpr int LSTR = NBLK * 2048;    // shorts per layer in ws (256KB)
}

struct Params { const float* in[39]; float* out; };

// fp32 -> bf16 (round-half-up) — repack-time only
DEV unsigned short f2bf(float f) {
  unsigned u = __builtin_bit_cast(unsigned, f);
  return (unsigned short)((u + 0x8000u) >> 16);
}
DEV float bf2f(unsigned short h) {
  unsigned u = ((unsigned)h) << 16;
  return __builtin_bit_cast(float, u);
}
DEV floatx4 mfma16(short8 a, short8 b, floatx4 c) {
  return __builtin_amdgcn_mfma_f32_16x16x32_bf16(a, b, c, 0, 0, 0);
}
// packed fp32->bf16 (RTNE), 2 values -> 1 dword. No builtin on gfx950.
DEV unsigned cvtpk(float lo, float hi) {
  unsigned r;
  asm("v_cvt_pk_bf16_f32 %0, %1, %2" : "=v"(r) : "v"(lo), "v"(hi));
  return r;
}
DEV float lo2f(unsigned u) { return __builtin_bit_cast(float, u << 16); }
DEV float hi2f(unsigned u) { return __builtin_bit_cast(float, u & 0xffff0000u); }
DEV short8 pack4(unsigned a, unsigned b, unsigned c, unsigned d) {
  uint4v u = {a, b, c, d};
  return __builtin_bit_cast(short8, u);
}

// ---------------------------------------------------------------------------
// Repack kernel: per (layer L, 32-hidden block blk) write 2048 shorts:
//   [0:512) W1 A-frag tile 2*blk | [512:1024) tile 2*blk+1
//   [1024:1536) W2 A-frag hi     | [1536:2048) W2 A-frag lo
// W1 A-frag lane (gg,rr): gg0=hi(W1[j0+rr][0..7]) gg1=lo gg2=hi(dup)
//                         gg3={b1_hi,b1_lo,0..} (bias folded, B supplies 1.0)
// W2 A-frag lane (gg,rr), rr<8: W2[rr][jsel(gg,i)],
//   jsel(gg,i)= j0 + (i<4 ? gg*4+i : 16+gg*4+(i-4))  — matches the FFN1
//   output fragment order so FFN2's B-operand is lane-local.
// ---------------------------------------------------------------------------
__global__ __launch_bounds__(64) void repack_kernel(Params P, short* ws) {
  const int wg = blockIdx.x;              // 8 layers * 64 blocks
  const int L = wg >> 6, blk = wg & 63;
  const int l = (int)threadIdx.x, gg = l >> 4, rr = l & 15;
  const float *W1p, *b1p, *W2p;
  if (L < 6) { W1p = P.in[7] + L * 16384;  b1p = P.in[8] + L * 2048;  W2p = P.in[9] + L * 16384; }
  else { int m = L - 6; W1p = P.in[25] + m * 16384; b1p = P.in[26] + m * 2048; W2p = P.in[27] + m * 16384; }
  short* out = ws + (L * 64 + blk) * 2048;
  const int j0 = blk * 32;
  short8 z = {0,0,0,0,0,0,0,0};
  for (int tt = 0; tt < 2; ++tt) {
    int j = j0 + tt * 16 + rr;
    short8 r = z;
    if (gg == 3) {
      unsigned short h = f2bf(b1p[j]);
      r[0] = (short)h; r[1] = (short)f2bf(b1p[j] - bf2f(h));
    } else {
      const float* p = W1p + j * 8;
#pragma unroll
      for (int i = 0; i < 8; ++i) {
        float v = p[i];
        unsigned short h = f2bf(v);
        r[i] = (short)((gg == 1) ? f2bf(v - bf2f(h)) : h);
      }
    }
    *(short8*)(out + tt * 512 + l * 8) = r;
  }
  short8 wh = z, wl = z;
  if (rr < 8) {
#pragma unroll
    for (int i = 0; i < 8; ++i) {
      int j = j0 + (i < 4 ? gg * 4 + i : 16 + gg * 4 + (i - 4));
      float v = W2p[rr * 2048 + j];
      unsigned short h = f2bf(v);
      wh[i] = (short)h;
      wl[i] = (short)f2bf(v - bf2f(h));
    }
  }
  *(short8*)(out + 1024 + l * 8) = wh;
  *(short8*)(out + 1536 + l * 8) = wl;
}

// ---------------------------------------------------------------------------
__global__ __launch_bounds__(NT, 2) void tdec_kernel(Params P, const short* ws) {
  const int b    = blockIdx.x;
  const int tid  = (int)threadIdx.x;
  const int lane = tid & 63;
  const int wave = tid >> 6;
  const int gg   = lane >> 4;   // k-group within MFMA
  const int rr   = lane & 15;   // row/col within 16-tile

  __shared__ float buf[T][D];
  __shared__ __align__(16) float X[64][D];   // zero-padded rows >= R
  __shared__ float Mem[64][D];
  __shared__ __align__(16) float Qs[64][D];
  __shared__ __align__(16) float Ks[64][D];
  __shared__ __align__(16) float Vs[64][D];
  __shared__ float ATT[64][D];
  // persistent per-row caches (rows appended at their step, frozen after):
  __shared__ __align__(16) float Q0s[64][D]; // enc-L0 Q of buf rows
  __shared__ __align__(16) float K0s[64][D]; // enc-L0 K
  __shared__ __align__(16) float V0s[64][D]; // enc-L0 V
  __shared__ __align__(16) float K6s[64][D]; // dec-L1 self K of buf rows
  __shared__ __align__(16) float V6s[64][D]; // dec-L1 self V
  __shared__ __align__(16) float D1[64][D];  // dec-L1 self-attn+LN output
  __shared__ __align__(16) float red[NW * 1024];  // FFN cross-wave partials 32KB
  __shared__ float wAll[10 * 288];
  __shared__ float lnp[40][D];
  __shared__ float b2all[8][D];
  __shared__ float fcw[SD][D];
  __shared__ float fcbv[SD];
  __shared__ float embw[D][SD];
  __shared__ float embbv[D];
  __shared__ float stv[SD];

  // ---------------- one-time staging of all small weights ----------------
  for (int o = tid; o < 2880; o += NT) {
    int a = o / 288, off = o - a * 288;
    const float *Wq, *Bq, *Wo, *Bo; int li;
    if (a < 6)              { li = a;            Wq=P.in[3];  Bq=P.in[4];  Wo=P.in[5];  Bo=P.in[6];  }
    else if (((a - 6) & 1) == 0) { li = (a-6)>>1; Wq=P.in[17]; Bq=P.in[18]; Wo=P.in[19]; Bo=P.in[20]; }
    else                    { li = (a-6)>>1;     Wq=P.in[21]; Bq=P.in[22]; Wo=P.in[23]; Bo=P.in[24]; }
    float v;
    if (off < 192)      v = Wq[li*192 + off];
    else if (off < 216) v = Bq[li*24  + off - 192];
    else if (off < 280) v = Wo[li*64  + off - 216];
    else                v = Bo[li*8   + off - 280];
    wAll[o] = v;
  }
  for (int o = tid; o < 320; o += NT) {
    int row = o >> 3, k = o & 7;
    const float* src;
    if (row < 24) { int li = row >> 2, w = row & 3;
      src = (w==0 ? P.in[11] : w==1 ? P.in[12] : w==2 ? P.in[13] : P.in[14]) + li*8;
    } else if (row < 26) src = (row == 24 ? P.in[15] : P.in[16]);
    else if (row < 38) { int q = row - 26, li = q / 6, w = q - li*6;
      src = (w==0?P.in[29]:w==1?P.in[30]:w==2?P.in[31]:w==3?P.in[32]:w==4?P.in[33]:P.in[34]) + li*8;
    } else src = (row == 38 ? P.in[35] : P.in[36]);
    lnp[row][k] = src[k];
  }
  if (tid < 64) { int row = tid >> 3, k = tid & 7;
    b2all[row][k] = (row < 6) ? P.in[10][row*8 + k] : P.in[28][(row-6)*8 + k]; }
  if (tid < 136) fcw[tid >> 3][tid & 7] = P.in[37][tid];
  if (tid < SD)  fcbv[tid] = P.in[38][tid];
  if (tid < 136) embw[tid / 17][tid % 17] = P.in[1][tid];
  if (tid < D)   embbv[tid] = P.in[2][tid];
  if (tid < D)   buf[0][tid] = P.in[0][b*D + tid];
  __syncthreads();

  const short8 zero8 = {0,0,0,0,0,0,0,0};
  const floatx4 zf4  = {0.f,0.f,0.f,0.f};

  // ---------------- helpers ----------------
  auto proj8 = [&](float (*dst)[D], const float (*src)[D], const float* w,
                   const float* bias, int R) {
    for (int o = tid; o < (R << 3); o += NT) {
      int r = o >> 3, d = o & 7;
      const float* wr = w + d * 8;
      const float* xr = src[r];
      float s = bias[d];
#pragma unroll
      for (int k = 0; k < 8; ++k) s += xr[k] * wr[k];
      dst[r][d] = s;
    }
  };

  // fixed-shift single-pass softmax (LN-bounded scores; exp(s-10) safe).
  // 4 threads per (p,h) when R<=32, else 2; shfl_xor combine; j-loop
  // unrolled x4 with float2 loads (r14).
  auto attn = [&](const float (*Qp)[D], const float (*Kp)[D],
                  const float (*Vp)[D], int R, bool causal) {
    if (R <= 32) {
      int p = tid >> 4, h2 = ((tid >> 2) & 3) << 1, e = tid & 3;
      if (p < R) {
        float q0 = Qp[p][h2]     * 0.70710678118654752f;
        float q1 = Qp[p][h2 + 1] * 0.70710678118654752f;
        int lim = causal ? p : (R - 1);
        float l = 0.f, a0 = 0.f, a1 = 0.f;
        int j = e;
        for (; j + 12 <= lim; j += 16) {
          float2 k0 = *(const float2*)&Kp[j     ][h2];
          float2 k1 = *(const float2*)&Kp[j +  4][h2];
          float2 k2 = *(const float2*)&Kp[j +  8][h2];
          float2 k3 = *(const float2*)&Kp[j + 12][h2];
          float2 v0 = *(const float2*)&Vp[j     ][h2];
          float2 v1 = *(const float2*)&Vp[j +  4][h2];
          float2 v2 = *(const float2*)&Vp[j +  8][h2];
          float2 v3 = *(const float2*)&Vp[j + 12][h2];
          float e0 = __expf(q0 * k0.x + q1 * k0.y - 10.f);
          float e1 = __expf(q0 * k1.x + q1 * k1.y - 10.f);
          float e2 = __expf(q0 * k2.x + q1 * k2.y - 10.f);
          float e3 = __expf(q0 * k3.x + q1 * k3.y - 10.f);
          l += e0; a0 += e0 * v0.x; a1 += e0 * v0.y;
          l += e1; a0 += e1 * v1.x; a1 += e1 * v1.y;
          l += e2; a0 += e2 * v2.x; a1 += e2 * v2.y;
          l += e3; a0 += e3 * v3.x; a1 += e3 * v3.y;
        }
        for (; j <= lim; j += 4) {
          float2 kk = *(const float2*)&Kp[j][h2];
          float2 vv = *(const float2*)&Vp[j][h2];
          float ev = __expf(q0 * kk.x + q1 * kk.y - 10.f);
          l += ev; a0 += ev * vv.x; a1 += ev * vv.y;
        }
        l  += __shfl_xor(l, 1);  l  += __shfl_xor(l, 2);
        a0 += __shfl_xor(a0, 1); a0 += __shfl_xor(a0, 2);
        a1 += __shfl_xor(a1, 1); a1 += __shfl_xor(a1, 2);
        if (e == 0) {
          float rl = 1.f / l;
          ATT[p][h2] = a0 * rl; ATT[p][h2 + 1] = a1 * rl;
        }
      }
    } else {
      int p = tid >> 3, h2 = ((tid >> 1) & 3) << 1, e = tid & 1;
      if (p < R) {
        float q0 = Qp[p][h2]     * 0.70710678118654752f;
        float q1 = Qp[p][h2 + 1] * 0.70710678118654752f;
        int lim = causal ? p : (R - 1);
        float l = 0.f, a0 = 0.f, a1 = 0.f;
        int j = e;
        for (; j + 6 <= lim; j += 8) {
          float2 k0 = *(const float2*)&Kp[j    ][h2];
          float2 k1 = *(const float2*)&Kp[j + 2][h2];
          float2 k2 = *(const float2*)&Kp[j + 4][h2];
          float2 k3 = *(const float2*)&Kp[j + 6][h2];
          float2 v0 = *(const float2*)&Vp[j    ][h2];
          float2 v1 = *(const float2*)&Vp[j + 2][h2];
          float2 v2 = *(const float2*)&Vp[j + 4][h2];
          float2 v3 = *(const float2*)&Vp[j + 6][h2];
          float e0 = __expf(q0 * k0.x + q1 * k0.y - 10.f);
          float e1 = __expf(q0 * k1.x + q1 * k1.y - 10.f);
          float e2 = __expf(q0 * k2.x + q1 * k2.y - 10.f);
          float e3 = __expf(q0 * k3.x + q1 * k3.y - 10.f);
          l += e0; a0 += e0 * v0.x; a1 += e0 * v0.y;
          l += e1; a0 += e1 * v1.x; a1 += e1 * v1.y;
          l += e2; a0 += e2 * v2.x; a1 += e2 * v2.y;
          l += e3; a0 += e3 * v3.x; a1 += e3 * v3.y;
        }
        for (; j <= lim; j += 2) {
          float2 kk = *(const float2*)&Kp[j][h2];
          float2 vv = *(const float2*)&Vp[j][h2];
          float ev = __expf(q0 * kk.x + q1 * kk.y - 10.f);
          l += ev; a0 += ev * vv.x; a1 += ev * vv.y;
        }
        l  += __shfl_xor(l, 1);
        a0 += __shfl_xor(a0, 1);
        a1 += __shfl_xor(a1, 1);
        if (e == 0) {
          float rl = 1.f / l;
          ATT[p][h2] = a0 * rl; ATT[p][h2 + 1] = a1 * rl;
        }
      }
    }
  };

  // out-projection + residual(res) + LN -> dst, one thread per row.
  // Caller must __syncthreads() afterwards.
  auto oproj_ln = [&](const float* wo, const float* bo, const float* g,
                      const float* bb, int R, const float (*res)[D],
                      float (*dst)[D]) {
    if (tid < R) {
      float o[8];
#pragma unroll
      for (int d = 0; d < 8; ++d) {
        float s = bo[d] + res[tid][d];
#pragma unroll
        for (int k = 0; k < 8; ++k) s += ATT[tid][k] * wo[d * 8 + k];
        o[d] = s;
      }
      float m = 0.f;
#pragma unroll
      for (int k = 0; k < 8; ++k) m += o[k];
      m *= 0.125f;
      float v = 0.f;
#pragma unroll
      for (int k = 0; k < 8; ++k) { float dm = o[k] - m; v += dm * dm; }
      float rs = rsqrtf(v * 0.125f + 1e-5f);
#pragma unroll
      for (int k = 0; k < 8; ++k) dst[tid][k] = (o[k] - m) * rs * g[k] + bb[k];
    }
  };

  auto ln_rows = [&](float (*dst)[D], const float (*src)[D], const float* g,
                     const float* bb, int R) {
    if (tid < R) {
      float o[8];
#pragma unroll
      for (int k = 0; k < 8; ++k) o[k] = src[tid][k];
      float m = 0.f;
#pragma unroll
      for (int k = 0; k < 8; ++k) m += o[k];
      m *= 0.125f;
      float v = 0.f;
#pragma unroll
      for (int k = 0; k < 8; ++k) { float dm = o[k] - m; v += dm * dm; }
      float rs = rsqrtf(v * 0.125f + 1e-5f);
#pragma unroll
      for (int k = 0; k < 8; ++k) dst[tid][k] = (o[k] - m) * rs * g[k] + bb[k];
    }
  };

  auto mha = [&](int a, float (*kvsrc)[D], bool causal, int R,
                 const float* g, const float* bb) {
    const float* wq = &wAll[a * 288];
    proj8(Qs, X,     wq +   0, wq + 192, R);
    proj8(Ks, kvsrc, wq +  64, wq + 200, R);
    proj8(Vs, kvsrc, wq + 128, wq + 208, R);
    __syncthreads();
    attn(Qs, Ks, Vs, R, causal);
    __syncthreads();
    oproj_ln(wq + 216, wq + 280, g, bb, R, X, X);
    __syncthreads();
  };

  // MHA computing ONLY row t of the output (K/V proj still full R rows).
  auto mha_row = [&](int a, float (*kvsrc)[D], int R, int t,
                     const float* g, const float* bb) {
    const float* wq = &wAll[a * 288];
    proj8(Ks, kvsrc, wq +  64, wq + 200, R);
    proj8(Vs, kvsrc, wq + 128, wq + 208, R);
    if (tid < 8) {                      // Q projection, row t only
      int d = tid;
      const float* wr = wq + d * 8;
      float s = wq[192 + d];
#pragma unroll
      for (int k = 0; k < 8; ++k) s += X[t][k] * wr[k];
      Qs[t][d] = s;
    }
    __syncthreads();
    if (tid < 32) {                     // attention row t: 8-way j-split
      int h2 = (tid >> 3) << 1, e = tid & 7;
      float q0 = Qs[t][h2]     * 0.70710678118654752f;
      float q1 = Qs[t][h2 + 1] * 0.70710678118654752f;
      float l = 0.f, a0 = 0.f, a1 = 0.f;
      int j = e;
      for (; j + 24 < R; j += 32) {
        float2 k0 = *(const float2*)&Ks[j     ][h2];
        float2 k1 = *(const float2*)&Ks[j +  8][h2];
        float2 k2 = *(const float2*)&Ks[j + 16][h2];
        float2 k3 = *(const float2*)&Ks[j + 24][h2];
        float2 v0 = *(const float2*)&Vs[j     ][h2];
        float2 v1 = *(const float2*)&Vs[j +  8][h2];
        float2 v2 = *(const float2*)&Vs[j + 16][h2];
        float2 v3 = *(const float2*)&Vs[j + 24][h2];
        float e0 = __expf(q0 * k0.x + q1 * k0.y - 10.f);
        float e1 = __expf(q0 * k1.x + q1 * k1.y - 10.f);
        float e2 = __expf(q0 * k2.x + q1 * k2.y - 10.f);
        float e3 = __expf(q0 * k3.x + q1 * k3.y - 10.f);
        l += e0; a0 += e0 * v0.x; a1 += e0 * v0.y;
        l += e1; a0 += e1 * v1.x; a1 += e1 * v1.y;
        l += e2; a0 += e2 * v2.x; a1 += e2 * v2.y;
        l += e3; a0 += e3 * v3.x; a1 += e3 * v3.y;
      }
      for (; j < R; j += 8) {
        float2 kk = *(const float2*)&Ks[j][h2];
        float2 vv = *(const float2*)&Vs[j][h2];
        float ev = __expf(q0 * kk.x + q1 * kk.y - 10.f);
        l += ev; a0 += ev * vv.x; a1 += ev * vv.y;
      }
      l  += __shfl_xor(l, 1);  l  += __shfl_xor(l, 2);  l  += __shfl_xor(l, 4);
      a0 += __shfl_xor(a0, 1); a0 += __shfl_xor(a0, 2); a0 += __shfl_xor(a0, 4);
      a1 += __shfl_xor(a1, 1); a1 += __shfl_xor(a1, 2); a1 += __shfl_xor(a1, 4);
      if (e == 0) {
        float rl = 1.f / l;
        ATT[t][h2] = a0 * rl; ATT[t][h2 + 1] = a1 * rl;
      }
    }
    __syncthreads();
    if (tid == 0) {                     // oproj + residual + LN, row t
      float o[8];
#pragma unroll
      for (int d = 0; d < 8; ++d) {
        float s = wq[280 + d] + X[t][d];
#pragma unroll
        for (int k = 0; k < 8; ++k) s += ATT[t][k] * wq[216 + d * 8 + k];
        o[d] = s;
      }
      float m = 0.f;
#pragma unroll
      for (int k = 0; k < 8; ++k) m += o[k];
      m *= 0.125f;
      float v = 0.f;
#pragma unroll
      for (int k = 0; k < 8; ++k) { float dm = o[k] - m; v += dm * dm; }
      float rs = rsqrtf(v * 0.125f + 1e-5f);
#pragma unroll
      for (int k = 0; k < 8; ++k) X[t][k] = (o[k] - m) * rs * g[k] + bb[k];
    }
    __syncthreads();
  };

  // FFN, swapped-operand form (r5 3-term arithmetic — FROZEN).
  auto ffn = [&](const short* wsL, const float* b2, const float* g,
                 const float* bb, int R, int Mt) {
    // issue block-0 fragment loads first; bx-setup VALU hides the latency
    const short* pb = wsL + (wave * BPW) * 2048;
    short8 a0  = *(const short8*)(pb + lane * 8);
    short8 a1  = *(const short8*)(pb + 512 + lane * 8);
    short8 w2h = *(const short8*)(pb + 1024 + lane * 8);
    short8 w2l = *(const short8*)(pb + 1536 + lane * 8);

    // B-frags (X^T) per r-tile; lane variant: gg0/1=x_hi, gg2=x_lo, gg3=ones
    short8 bx[4];
#pragma unroll
    for (int mt = 0; mt < 4; ++mt) {
      short8 v = zero8;
      if (mt < Mt) {
        if (gg == 3) { v[0] = (short)0x3F80; v[1] = (short)0x3F80; }
        else {
          int r = mt * 16 + rr;
          float4 A = *(const float4*)&X[r][0];
          float4 Bv = *(const float4*)&X[r][4];
          unsigned u0 = cvtpk(A.x, A.y), u1 = cvtpk(A.z, A.w);
          unsigned u2 = cvtpk(Bv.x, Bv.y), u3 = cvtpk(Bv.z, Bv.w);
          if (gg == 2) {
            unsigned l0 = cvtpk(A.x - lo2f(u0), A.y - hi2f(u0));
            unsigned l1 = cvtpk(A.z - lo2f(u1), A.w - hi2f(u1));
            unsigned l2 = cvtpk(Bv.x - lo2f(u2), Bv.y - hi2f(u2));
            unsigned l3 = cvtpk(Bv.z - lo2f(u3), Bv.w - hi2f(u3));
            v = pack4(l0, l1, l2, l3);
          } else {
            v = pack4(u0, u1, u2, u3);
          }
        }
      }
      bx[mt] = v;
    }

    floatx4 acc[4] = {zf4, zf4, zf4, zf4};
    for (int blkI = 0; blkI < BPW; ++blkI) {
      short8 na0 = zero8, na1 = zero8, nw2h = zero8, nw2l = zero8;
      if (blkI + 1 < BPW) {            // prefetch next block's fragments
        const short* pn = pb + (blkI + 1) * 2048;
        na0  = *(const short8*)(pn + lane * 8);
        na1  = *(const short8*)(pn + 512 + lane * 8);
        nw2h = *(const short8*)(pn + 1024 + lane * 8);
        nw2l = *(const short8*)(pn + 1536 + lane * 8);
      }
#pragma unroll
      for (int mt = 0; mt < 4; ++mt) {
        if (mt < Mt) {
          floatx4 h0 = mfma16(a0, bx[mt], zf4);   // rows j0..j0+15, cols=pos
          floatx4 h1 = mfma16(a1, bx[mt], zf4);   // rows j0+16..j0+31
          float v0 = fmaxf(h0[0], 0.f), v1 = fmaxf(h0[1], 0.f);
          float v2 = fmaxf(h0[2], 0.f), v3 = fmaxf(h0[3], 0.f);
          float v4 = fmaxf(h1[0], 0.f), v5 = fmaxf(h1[1], 0.f);
          float v6 = fmaxf(h1[2], 0.f), v7 = fmaxf(h1[3], 0.f);
          unsigned u0 = cvtpk(v0, v1), u1 = cvtpk(v2, v3);
          unsigned u2 = cvtpk(v4, v5), u3 = cvtpk(v6, v7);
          unsigned l0 = cvtpk(v0 - lo2f(u0), v1 - hi2f(u0));
          unsigned l1 = cvtpk(v2 - lo2f(u1), v3 - hi2f(u1));
          unsigned l2 = cvtpk(v4 - lo2f(u2), v5 - hi2f(u2));
          unsigned l3 = cvtpk(v6 - lo2f(u3), v7 - hi2f(u3));
          short8 ah = pack4(u0, u1, u2, u3);
          short8 al = pack4(l0, l1, l2, l3);
          // A-operand = W2 (rows = d), B-operand = h (cols = pos):
          // D[row=d][col=pos] matches the reduce below.
          acc[mt] = mfma16(w2h, ah, acc[mt]);
          acc[mt] = mfma16(w2h, al, acc[mt]);
          acc[mt] = mfma16(w2l, ah, acc[mt]);
        }
      }
      a0 = na0; a1 = na1; w2h = nw2h; w2l = nw2l;
    }

    // cross-wave reduce + residual + bias + LN, fused per row
#pragma unroll
    for (int mt = 0; mt < 4; ++mt)
      if (mt < Mt)
        *(floatx4*)&red[(((wave << 2) + mt) << 8) + (lane << 2)] = acc[mt];
    __syncthreads();
    if (tid < R) {
      int r = tid, mt = r >> 4, rl = r & 15;
      float o[8];
#pragma unroll
      for (int d = 0; d < 8; ++d) {
        float s = X[r][d] + b2[d];
        // acc layout: lane (gg=d>>2, rr=rl) reg (d&3) holds out^T[d][mt*16+rl]
        int base = (mt << 8) + ((((d >> 2) << 4) + rl) << 2) + (d & 3);
#pragma unroll
        for (int w = 0; w < NW; ++w) s += red[(w << 10) + base];
        o[d] = s;
      }
      float m = 0.f;
#pragma unroll
      for (int k = 0; k < 8; ++k) m += o[k];
      m *= 0.125f;
      float var = 0.f;
#pragma unroll
      for (int k = 0; k < 8; ++k) { float dm = o[k] - m; var += dm * dm; }
      float rs = rsqrtf(var * 0.125f + 1e-5f);
#pragma unroll
      for (int k = 0; k < 8; ++k) X[r][k] = (o[k] - m) * rs * g[k] + bb[k];
    }
    __syncthreads();
  };

  // FFN computing ONLY row t (column 0 of tile 0; k-sum column-independent
  // so the row-t result is bit-identical to full ffn).
  auto ffn_row = [&](const short* wsL, const float* b2, const float* g,
                     const float* bb, int t) {
    const short* pb = wsL + (wave * BPW) * 2048;
    short8 a0  = *(const short8*)(pb + lane * 8);
    short8 a1  = *(const short8*)(pb + 512 + lane * 8);
    short8 w2h = *(const short8*)(pb + 1024 + lane * 8);
    short8 w2l = *(const short8*)(pb + 1536 + lane * 8);

    short8 bx = zero8;
    if (gg == 3) { bx[0] = (short)0x3F80; bx[1] = (short)0x3F80; }
    else if (rr == 0) {
      float4 A = *(const float4*)&X[t][0];
      float4 Bv = *(const float4*)&X[t][4];
      unsigned u0 = cvtpk(A.x, A.y), u1 = cvtpk(A.z, A.w);
      unsigned u2 = cvtpk(Bv.x, Bv.y), u3 = cvtpk(Bv.z, Bv.w);
      if (gg == 2) {
        unsigned l0 = cvtpk(A.x - lo2f(u0), A.y - hi2f(u0));
        unsigned l1 = cvtpk(A.z - lo2f(u1), A.w - hi2f(u1));
        unsigned l2 = cvtpk(Bv.x - lo2f(u2), Bv.y - hi2f(u2));
        unsigned l3 = cvtpk(Bv.z - lo2f(u3), Bv.w - hi2f(u3));
        bx = pack4(l0, l1, l2, l3);
      } else {
        bx = pack4(u0, u1, u2, u3);
      }
    }

    floatx4 acc = zf4;
    for (int blkI = 0; blkI < BPW; ++blkI) {
      short8 na0 = zero8, na1 = zero8, nw2h = zero8, nw2l = zero8;
      if (blkI + 1 < BPW) {
        const short* pn = pb + (blkI + 1) * 2048;
        na0  = *(const short8*)(pn + lane * 8);
        na1  = *(const short8*)(pn + 512 + lane * 8);
        nw2h = *(const short8*)(pn + 1024 + lane * 8);
        nw2l = *(const short8*)(pn + 1536 + lane * 8);
      }
      floatx4 h0 = mfma16(a0, bx, zf4);
      floatx4 h1 = mfma16(a1, bx, zf4);
      float v0 = fmaxf(h0[0], 0.f), v1 = fmaxf(h0[1], 0.f);
      float v2 = fmaxf(h0[2], 0.f), v3 = fmaxf(h0[3], 0.f);
      float v4 = fmaxf(h1[0], 0.f), v5 = fmaxf(h1[1], 0.f);
      float v6 = fmaxf(h1[2], 0.f), v7 = fmaxf(h1[3], 0.f);
      unsigned u0 = cvtpk(v0, v1), u1 = cvtpk(v2, v3);
      unsigned u2 = cvtpk(v4, v5), u3 = cvtpk(v6, v7);
      unsigned l0 = cvtpk(v0 - lo2f(u0), v1 - hi2f(u0));
      unsigned l1 = cvtpk(v2 - lo2f(u1), v3 - hi2f(u1));
      unsigned l2 = cvtpk(v4 - lo2f(u2), v5 - hi2f(u2));
      unsigned l3 = cvtpk(v6 - lo2f(u3), v7 - hi2f(u3));
      short8 ah = pack4(u0, u1, u2, u3);
      short8 al = pack4(l0, l1, l2, l3);
      acc = mfma16(w2h, ah, acc);
      acc = mfma16(w2h, al, acc);
      acc = mfma16(w2l, ah, acc);
      a0 = na0; a1 = na1; w2h = nw2h; w2l = nw2l;
    }

    *(floatx4*)&red[(wave << 10) + (lane << 2)] = acc;
    __syncthreads();
    if (tid == 0) {
      float o[8];
#pragma unroll
      for (int d = 0; d < 8; ++d) {
        float s = X[t][d] + b2[d];
        int base = ((d >> 2) << 6) + (d & 3);   // lane (gg=d>>2, rr=0) reg d&3
#pragma unroll
        for (int w = 0; w < NW; ++w) s += red[(w << 10) + base];
        o[d] = s;
      }
      float m = 0.f;
#pragma unroll
      for (int k = 0; k < 8; ++k) m += o[k];
      m *= 0.125f;
      float var = 0.f;
#pragma unroll
      for (int k = 0; k < 8; ++k) { float dm = o[k] - m; var += dm * dm; }
      float rs = rsqrtf(var * 0.125f + 1e-5f);
#pragma unroll
      for (int k = 0; k < 8; ++k) X[t][k] = (o[k] - m) * rs * g[k] + bb[k];
    }
    __syncthreads();
  };

  // ---------------- the 60-step scan ----------------
  for (int t = 0; t < T; ++t) {
    const int R = t + 1;
    const int Mt = (R + 15) >> 4;

    // X <- buf (zero-pad rows >= R); append per-row caches for row t
    // (buf[t] is frozen: enc-L0 Q/K/V and dec-L1-self K/V never change).
    for (int o = tid; o < 512; o += NT) {
      int r = o >> 3, d = o & 7;
      X[r][d] = (r < R) ? buf[r][d] : 0.f;
    }
    if (tid < 40) {
      int sel = tid >> 3, d = tid & 7;
      const float* wq0 = &wAll[0];
      const float* wq6 = &wAll[6 * 288];
      const float* w; float bias; float* dst;
      if (sel == 0)      { w = wq0 + 0   + d * 8; bias = wq0[192 + d]; dst = &Q0s[t][d]; }
      else if (sel == 1) { w = wq0 + 64  + d * 8; bias = wq0[200 + d]; dst = &K0s[t][d]; }
      else if (sel == 2) { w = wq0 + 128 + d * 8; bias = wq0[208 + d]; dst = &V0s[t][d]; }
      else if (sel == 3) { w = wq6 + 64  + d * 8; bias = wq6[200 + d]; dst = &K6s[t][d]; }
      else               { w = wq6 + 128 + d * 8; bias = wq6[208 + d]; dst = &V6s[t][d]; }
      float s = bias;
#pragma unroll
      for (int k = 0; k < 8; ++k) s += buf[t][k] * w[k];
      *dst = s;
    }
    __syncthreads();

    // encoder layer 0: Q/K/V cached (buf rows frozen) — no proj phase
    attn(Q0s, K0s, V0s, R, false);
    __syncthreads();
    oproj_ln(&wAll[0] + 216, &wAll[0] + 280, lnp[0], lnp[1], R, X, X);
    __syncthreads();
    ffn(ws + 0 * LSTR, b2all[0], lnp[2], lnp[3], R, Mt);

    // encoder layers 1..5
    for (int li = 1; li < 6; ++li) {
      mha(li, X, false, R, lnp[li * 4 + 0], lnp[li * 4 + 1]);
      ffn(ws + li * LSTR, b2all[li], lnp[li * 4 + 2], lnp[li * 4 + 3], R, Mt);
    }
    ln_rows(X, X, lnp[24], lnp[25], R);
    __syncthreads();

    // Mem <- encoder output; fold in dec-L1-self Q projection of row t
    for (int o = tid; o < (R << 3); o += NT) {
      int r = o >> 3, d = o & 7;
      Mem[r][d] = X[r][d];
    }
    if (tid < 8) {
      const float* wq6 = &wAll[6 * 288];
      int d = tid;
      float s = wq6[192 + d];
#pragma unroll
      for (int k = 0; k < 8; ++k) s += buf[t][k] * wq6[d * 8 + k];
      Qs[t][d] = s;
    }
    __syncthreads();

    // decoder L1 SELF-attention: incremental (output rows frozen after their
    // step — causal over frozen buf). Compute only row t into D1[t].
    if (tid < 32) {
      int h2 = (tid >> 3) << 1, e = tid & 7;
      float q0 = Qs[t][h2]     * 0.70710678118654752f;
      float q1 = Qs[t][h2 + 1] * 0.70710678118654752f;
      float l = 0.f, a0 = 0.f, a1 = 0.f;
      int j = e;
      for (; j + 24 < R; j += 32) {
        float2 k0 = *(const float2*)&K6s[j     ][h2];
        float2 k1 = *(const float2*)&K6s[j +  8][h2];
        float2 k2 = *(const float2*)&K6s[j + 16][h2];
        float2 k3 = *(const float2*)&K6s[j + 24][h2];
        float2 v0 = *(const float2*)&V6s[j     ][h2];
        float2 v1 = *(const float2*)&V6s[j +  8][h2];
        float2 v2 = *(const float2*)&V6s[j + 16][h2];
        float2 v3 = *(const float2*)&V6s[j + 24][h2];
        float e0 = __expf(q0 * k0.x + q1 * k0.y - 10.f);
        float e1 = __expf(q0 * k1.x + q1 * k1.y - 10.f);
        float e2 = __expf(q0 * k2.x + q1 * k2.y - 10.f);
        float e3 = __expf(q0 * k3.x + q1 * k3.y - 10.f);
        l += e0; a0 += e0 * v0.x; a1 += e0 * v0.y;
        l += e1; a0 += e1 * v1.x; a1 += e1 * v1.y;
        l += e2; a0 += e2 * v2.x; a1 += e2 * v2.y;
        l += e3; a0 += e3 * v3.x; a1 += e3 * v3.y;
      }
      for (; j < R; j += 8) {
        float2 kk = *(const float2*)&K6s[j][h2];
        float2 vv = *(const float2*)&V6s[j][h2];
        float ev = __expf(q0 * kk.x + q1 * kk.y - 10.f);
        l += ev; a0 += ev * vv.x; a1 += ev * vv.y;
      }
      l  += __shfl_xor(l, 1);  l  += __shfl_xor(l, 2);  l  += __shfl_xor(l, 4);
      a0 += __shfl_xor(a0, 1); a0 += __shfl_xor(a0, 2); a0 += __shfl_xor(a0, 4);
      a1 += __shfl_xor(a1, 1); a1 += __shfl_xor(a1, 2); a1 += __shfl_xor(a1, 4);
      if (e == 0) {
        float rl = 1.f / l;
        ATT[t][h2] = a0 * rl; ATT[t][h2 + 1] = a1 * rl;
      }
    }
    __syncthreads();
    if (tid == 0) {                     // oproj + residual(buf[t]) + LN -> D1[t]
      const float* wq6 = &wAll[6 * 288];
      float o[8];
#pragma unroll
      for (int d = 0; d < 8; ++d) {
        float s = wq6[280 + d] + buf[t][d];
#pragma unroll
        for (int k = 0; k < 8; ++k) s += ATT[t][k] * wq6[216 + d * 8 + k];
        o[d] = s;
      }
      float m = 0.f;
#pragma unroll
      for (int k = 0; k < 8; ++k) m += o[k];
      m *= 0.125f;
      float v = 0.f;
#pragma unroll
      for (int k = 0; k < 8; ++k) { float dm = o[k] - m; v += dm * dm; }
      float rs = rsqrtf(v * 0.125f + 1e-5f);
#pragma unroll
      for (int k = 0; k < 8; ++k) D1[t][k] = (o[k] - m) * rs * lnp[26][k] + lnp[27][k];
    }
    __syncthreads();

    // decoder L1 cross-attention: queries+residual from D1, output -> X
    {
      const float* wq7 = &wAll[7 * 288];
      proj8(Qs, D1,  wq7 +   0, wq7 + 192, R);
      proj8(Ks, Mem, wq7 +  64, wq7 + 200, R);
      proj8(Vs, Mem, wq7 + 128, wq7 + 208, R);
      __syncthreads();
      attn(Qs, Ks, Vs, R, false);
      __syncthreads();
      oproj_ln(wq7 + 216, wq7 + 280, lnp[28], lnp[29], R, D1, X);
      __syncthreads();
    }
    ffn(ws + 6 * LSTR, b2all[6], lnp[30], lnp[31], R, Mt);

    // decoder layer 2: ONLY row t is ever consumed downstream
    mha_row(8, X,   R, t, lnp[32], lnp[33]);
    mha_row(9, Mem, R, t, lnp[34], lnp[35]);
    ffn_row(ws + 7 * LSTR, b2all[7], lnp[36], lnp[37], t);

    // final LN (row t) + st = y[t] @ fc_W^T + fc_b -> out; embed to buf[t+1]
    if (tid == 0) {
      float o[8];
#pragma unroll
      for (int k = 0; k < 8; ++k) o[k] = X[t][k];
      float m = 0.f;
#pragma unroll
      for (int k = 0; k < 8; ++k) m += o[k];
      m *= 0.125f;
      float v = 0.f;
#pragma unroll
      for (int k = 0; k < 8; ++k) { float dm = o[k] - m; v += dm * dm; }
      float rs = rsqrtf(v * 0.125f + 1e-5f);
#pragma unroll
      for (int k = 0; k < 8; ++k) X[t][k] = (o[k] - m) * rs * lnp[38][k] + lnp[39][k];
    }
    __syncthreads();
    if (tid < SD) {
      float s = fcbv[tid];
#pragma unroll
      for (int k = 0; k < 8; ++k) s += X[t][k] * fcw[tid][k];
      stv[tid] = s;
      P.out[(b * T + t) * SD + tid] = s;
    }
    __syncthreads();
    if (t + 1 < T && tid < D) {
      float s = embbv[tid];
#pragma unroll
      for (int k = 0; k < SD; ++k) s += stv[k] * embw[tid][k];
      buf[t + 1][tid] = s;
    }
    __syncthreads();
  }
}

extern "C" void kernel_launch(void* const* d_in, const int* in_sizes, int n_in,
                              void* d_out, int out_size, void* d_ws, size_t ws_size,
                              hipStream_t stream) {
  (void)in_sizes; (void)n_in; (void)ws_size; (void)out_size;
  Params P;
  for (int i = 0; i < 39; ++i) P.in[i] = (const float*)d_in[i];
  P.out = (float*)d_out;
  short* ws = (short*)d_ws;   // 8 layers * 256KB = 2MB of packed fragments
  repack_kernel<<<dim3(8 * NBLK), dim3(64), 0, stream>>>(P, ws);
  tdec_kernel<<<dim3(128), dim3(NT), 0, stream>>>(P, ws);
}